// Round 9
// baseline (375.319 us; speedup 1.0000x reference)
//
#include <hip/hip_runtime.h>
#include <cstdint>
#include <cstddef>

#define D_HEAD   64
#define NHEAD    16
#define DMODEL   1024
#define SLEN     2048
#define BSZ      4
#define MROWS    (SLEN*BSZ)            // 8192
#define NQKVB    (NHEAD*(3*D_HEAD+1))  // 3088
#define NQPAD    3328                  // padded to 13*256 for the 256-tile GEMM
#define EPSV     1e-5f
#define SCALEV   0.125f                // 1/sqrt(64)
#define CHK      64                    // chunk length
#define NCH      (SLEN/CHK)            // 32

typedef short bf16x8 __attribute__((ext_vector_type(8)));
typedef float f32x4  __attribute__((ext_vector_type(4)));

__device__ __forceinline__ unsigned short f2bf(float f){
  unsigned int u = __float_as_uint(f);
  u = (u + 0x7fffu + ((u >> 16) & 1u)) >> 16;   // RNE
  return (unsigned short)u;
}
__device__ __forceinline__ float bf2f(unsigned short s){
  return __uint_as_float(((unsigned int)s) << 16);
}

__device__ __forceinline__ void gload_lds16(const unsigned short* g, unsigned short* l){
  __builtin_amdgcn_global_load_lds((const __attribute__((address_space(1))) void*)g,
                                   (__attribute__((address_space(3))) void*)l, 16, 0, 0);
}

// swizzled in-row offset: XOR the 8-element block index with (row&7)
#define SWZ(row, col) ((col) ^ (((row)&7)<<3))

// ------------------------------------------------------------------ fused casts
__global__ void cast3_kernel(const float* __restrict__ s0, unsigned short* __restrict__ d0, int n0,
                             const float* __restrict__ s1, unsigned short* __restrict__ d1, int n1,
                             const float* __restrict__ s2, unsigned short* __restrict__ d2, int n2){
  int total = n0 + n1 + n2;
  int stride = gridDim.x * blockDim.x;
  for (int i = blockIdx.x*blockDim.x + threadIdx.x; i < total; i += stride){
    const float* s; unsigned short* d; int j = i;
    if (j < n0){ s = s0; d = d0; }
    else if (j < n0 + n1){ j -= n0; s = s1; d = d1; }
    else { j -= n0 + n1; s = s2; d = d2; }
    float4 f = ((const float4*)s)[j];
    ushort4 u;
    u.x = f2bf(f.x); u.y = f2bf(f.y); u.z = f2bf(f.z); u.w = f2bf(f.w);
    ((ushort4*)d)[j] = u;
  }
}

// ------------------------------------------------------------------ GEMM (NT), 256x256 8-phase template
// BM=BN=256, BK=64, 8 waves (2M x 4N), 512 threads, 128 KiB LDS double-buffer.
// LDS tiles XOR-swizzled via pre-swizzled global SOURCE; reads apply the same XOR.
// Counted vmcnt(2) at phases 4/8. 2D-chunked XCD mapping keeps each XCD's A slab
// L2-resident (FETCH 123->47 MB measured r6); kernel is schedule-bound at ~28%
// MfmaUtil, consistent with the template ceiling at K=1024 / 1.625-round grids.
// SPLITK: first/second half of the grid computes K/2 depth into C/C2 (fp32).
#define GBAR  do{ asm volatile("" ::: "memory"); __builtin_amdgcn_s_barrier(); asm volatile("" ::: "memory"); }while(0)
#define WVM2  asm volatile("s_waitcnt vmcnt(2)" ::: "memory")
#define WLG0  asm volatile("s_waitcnt lgkmcnt(0)" ::: "memory")
#define WLG8  asm volatile("s_waitcnt lgkmcnt(8)" ::: "memory")

#define LDA(sb_, mih_) do{ \
  _Pragma("unroll") \
  for (int m2 = 0; m2 < 4; ++m2) \
    _Pragma("unroll") \
    for (int ks = 0; ks < 2; ++ks) \
      aF[m2][ks] = frag(sb_, wmi*128 + (mih_)*64 + m2*16 + lm, ks); \
}while(0)

#define LDB(sb_, nih_) do{ \
  _Pragma("unroll") \
  for (int n2 = 0; n2 < 2; ++n2) \
    _Pragma("unroll") \
    for (int ks = 0; ks < 2; ++ks) \
      bF[(nih_)*2+n2][ks] = frag(sb_, wni*64 + (nih_)*32 + n2*16 + lm, ks); \
}while(0)

#define MMA(mih_, nih_) do{ \
  __builtin_amdgcn_s_setprio(1); \
  _Pragma("unroll") \
  for (int m2 = 0; m2 < 4; ++m2) \
    _Pragma("unroll") \
    for (int n2 = 0; n2 < 2; ++n2) \
      _Pragma("unroll") \
      for (int ks = 0; ks < 2; ++ks) \
        acc[(mih_)*4+m2][(nih_)*2+n2] = __builtin_amdgcn_mfma_f32_16x16x32_bf16( \
            aF[m2][ks], bF[(nih_)*2+n2][ks], acc[(mih_)*4+m2][(nih_)*2+n2], 0, 0, 0); \
  __builtin_amdgcn_s_setprio(0); \
}while(0)

template<bool OUT_BF16, bool SPLITK>
__global__ __launch_bounds__(512, 2) void gemm8p_kernel(
    const unsigned short* __restrict__ A, const unsigned short* __restrict__ B,
    void* __restrict__ C, void* __restrict__ C2, int N, int K, int lda, int tm){
  __shared__ __align__(16) unsigned short sA[2][256*64];
  __shared__ __align__(16) unsigned short sB[2][256*64];
  int tid = threadIdx.x;
  int wv = tid >> 6, ln = tid & 63, lm = ln & 15, quad = ln >> 4;
  // 2D-chunked bijective XCD mapping (requires tm%8==0; grid%8==0):
  //   xcd = wg&7 owns bm in [xcd*CM, (xcd+1)*CM), bn-major walk.
  int wg = blockIdx.x;
  int kh = 0;
  if (SPLITK){ int half = gridDim.x >> 1; if (wg >= half){ kh = 1; wg -= half; } }
  int xcd = wg & 7, l = wg >> 3;
  int CM = tm >> 3;
  int bn = l / CM, bm = xcd*CM + (l - bn*CM);
  int m0 = bm << 8, n0 = bn << 8;
  int wmi = wv >> 2, wni = wv & 3;
  const unsigned short* Ag = A + (size_t)m0*lda + (size_t)kh*K;
  const unsigned short* Bg = B + (size_t)n0*lda + (size_t)kh*K;

  f32x4 acc[8][4] = {};
  bf16x8 aF[4][2], bF[4][2];

  // iteration-invariant staging geometry: round r covers linear elem-blocks
  // e = r*512 + wv*64 + ln ; row = e>>3 ; cb = e&7 ; source col-block inverse-swizzled.
  int e0 = wv*64 + ln;
  int r0row = e0 >> 3, r0cb = e0 & 7;
  int e1 = 512 + e0;
  int r1row = e1 >> 3, r1cb = e1 & 7;
  size_t gsrc0 = (size_t)r0row*lda + ((r0cb ^ (r0row & 7)) << 3);
  size_t gsrc1 = (size_t)r1row*lda + ((r1cb ^ (r1row & 7)) << 3);
  int ldst0 = (wv*64) * 8;           // wave-uniform LDS elem offsets
  int ldst1 = (512 + wv*64) * 8;

  auto stage = [&](const unsigned short* g, unsigned short* sb, int h, int kt){
    gload_lds16(g + (size_t)h*128*lda + kt + gsrc0, sb + h*8192 + ldst0);
    gload_lds16(g + (size_t)h*128*lda + kt + gsrc1, sb + h*8192 + ldst1);
  };
  auto frag = [&](const unsigned short* sb, int row, int ks)->bf16x8 {
    return *(const bf16x8*)(sb + row*64 + ((((ks<<2)+quad) ^ (row & 7)) << 3));
  };

  // prologue: tile0 -> buf0 (4 half-tiles), tile1 A-h0 -> buf1; publish tile0.
  stage(Ag, sA[0], 0, 0);
  stage(Ag, sA[0], 1, 0);
  stage(Bg, sB[0], 0, 0);
  stage(Bg, sB[0], 1, 0);
  stage(Ag, sA[1], 0, 64);
  WVM2;
  GBAR;

  int nit = K >> 7;                   // 2 K-tiles (BK=64) per iteration
  for (int i = 0; i < nit; ++i){
    int k1 = (i<<7) + 64;             // odd tile of this iteration
    int k2 = ((i<<7) + 128) & (K-1);  // next even tile (wraps harmlessly at end)
    int k3 = ((i<<7) + 192) & (K-1);  // next odd tile

    // phase 1: Q(mi0-3 x ni0-1) on buf0
    LDA(sA[0], 0); LDB(sB[0], 0);
    stage(Ag, sA[1], 1, k1);
    WLG8;
    GBAR; WLG0; MMA(0,0); GBAR;
    // phase 2: Q(mi0-3 x ni2-3)
    LDB(sB[0], 1);
    stage(Bg, sB[1], 0, k1);
    GBAR; WLG0; MMA(0,1); GBAR;
    // phase 3: Q(mi4-7 x ni0-1)
    LDA(sA[0], 1);
    stage(Bg, sB[1], 1, k1);
    GBAR; WLG0; MMA(1,0); GBAR;
    // phase 4: Q(mi4-7 x ni2-3); publish buf1
    stage(Ag, sA[0], 0, k2);
    GBAR; MMA(1,1); WVM2; GBAR;
    // phase 5: buf1
    LDA(sA[1], 0); LDB(sB[1], 0);
    stage(Ag, sA[0], 1, k2);
    WLG8;
    GBAR; WLG0; MMA(0,0); GBAR;
    // phase 6
    LDB(sB[1], 1);
    stage(Bg, sB[0], 0, k2);
    GBAR; WLG0; MMA(0,1); GBAR;
    // phase 7
    LDA(sA[1], 1);
    stage(Bg, sB[0], 1, k2);
    GBAR; WLG0; MMA(1,0); GBAR;
    // phase 8: publish buf0 (next even tile)
    stage(Ag, sA[1], 0, k3);
    GBAR; MMA(1,1); WVM2; GBAR;
  }
  asm volatile("s_waitcnt vmcnt(0)" ::: "memory");  // drain trailing LDS-DMA before exit

  float* Cf = (float*)((SPLITK && kh) ? C2 : C);
  #pragma unroll
  for (int mi = 0; mi < 8; ++mi){
    int rowm = m0 + wmi*128 + mi*16 + quad*4;
    #pragma unroll
    for (int ni = 0; ni < 4; ++ni){
      int col = n0 + wni*64 + ni*16 + lm;
      size_t cb = (size_t)rowm * N + col;
      #pragma unroll
      for (int rr = 0; rr < 4; ++rr){
        float v = acc[mi][ni][rr];
        if (OUT_BF16) ((unsigned short*)C)[cb + (size_t)rr*N] = f2bf(v);
        else          Cf[cb + (size_t)rr*N] = v;
      }
    }
  }
}

#undef LDA
#undef LDB
#undef MMA
#undef GBAR
#undef WVM2
#undef WLG0
#undef WLG8

// ------------------------------------------------------------------ segmented cumsum over l
// NSEG=64 (SEGL=32): 4096 waves -> 16 waves/CU for the serial latency chains.
// kn is RECOMPUTED from qkvb_bf (bit-exact vs the old prep path: same bf16 inputs,
// same expf, same shuffle order) — kills the kb fp32 round-trip entirely.
#define NSEG 64
#define SEGL (SLEN/NSEG)   // 32
__global__ __launch_bounds__(64) void segsum_kernel(
    const unsigned short* __restrict__ qkvb, float* __restrict__ S){
  int bh = blockIdx.x, seg = blockIdx.y, ln = threadIdx.x;
  int b = bh >> 4, h = bh & 15;
  float s = 0.f;
  for (int i = 0; i < SEGL; ++i){
    int t = seg*SEGL + i;
    size_t rb = (size_t)(t*4+b) * NQPAD + (size_t)h*193;
    float kr = bf2f(qkvb[rb + 64 + ln]);
    float k1 = kr > 0.f ? kr + 1.f : __expf(kr);   // elu(x)+1
    float sk = k1;
    #pragma unroll
    for (int off = 1; off < 64; off <<= 1) sk += __shfl_xor(sk, off, 64);
    s += k1 / sk;
  }
  S[((size_t)bh*NSEG + seg)*64 + ln] = s;
}

// ------------------------------------------------------------------ fused prep + scan + denominators
// Recomputes qn/kn from qkvb_bf (bit-exact vs old prep), walks the inclusive
// cumsum, computes the three denominator reductions, and writes ALL downstream
// inputs: qb16/vb16 (bf16), kb16 (normalized bf16, swizzled), scal.
__global__ __launch_bounds__(64) void scan_kden_kernel(
    const unsigned short* __restrict__ qkvb, const float* __restrict__ S,
    unsigned short* __restrict__ qb16, unsigned short* __restrict__ vb16,
    unsigned short* __restrict__ kb16, float4* __restrict__ scal){
  int bh = blockIdx.x, seg = blockIdx.y, ln = threadIdx.x;
  int b = bh >> 4, h = bh & 15;
  float acc = 0.f;
  for (int s = 0; s < seg; ++s) acc += S[((size_t)bh*NSEG + s)*64 + ln];
  for (int i = 0; i < SEGL; ++i){
    int t = seg*SEGL + i;
    size_t rb = (size_t)(t*4+b) * NQPAD + (size_t)h*193;
    float qr = bf2f(qkvb[rb + ln]);
    float kr = bf2f(qkvb[rb + 64 + ln]);
    float vr = bf2f(qkvb[rb + 128 + ln]);
    float q1 = qr > 0.f ? qr + 1.f : __expf(qr);   // elu(x)+1
    float k1 = kr > 0.f ? kr + 1.f : __expf(kr);
    float sq = q1, sk = k1;
    #pragma unroll
    for (int off = 1; off < 64; off <<= 1){
      sq += __shfl_xor(sq, off, 64);
      sk += __shfl_xor(sk, off, 64);
    }
    float qn = q1 / sq, kn = k1 / sk;
    acc += kn;
    float a = acc;
    float d0 = (a - kn)*kn, d1 = a*qn, d2 = kn*qn;
    #pragma unroll
    for (int off = 1; off < 64; off <<= 1){
      d0 += __shfl_xor(d0, off, 64);
      d1 += __shfl_xor(d1, off, 64);
      d2 += __shfl_xor(d2, off, 64);
    }
    float kd  = (t == 0) ? 1.f : d0;
    float inv = 1.f / (kd + EPSV);
    float kf = kn * inv;
    size_t row = ((size_t)bh*SLEN + t)*64;
    qb16[row + SWZ(t, ln)] = f2bf(qn);
    vb16[row + ln] = f2bf(vr);
    kb16[row + SWZ(t, ln)] = f2bf(kf);
    if (ln == 0){
      float br = bf2f(qkvb[rb + 192]);
      float sb = 1.f / (1.f + __expf(-br));
      scal[(size_t)bh*SLEN + t] = make_float4(sb * kd, d2 * inv, SCALEV/(d1 + EPSV), 0.f);
    }
  }
}

// ------------------------------------------------------------------ precompute per (bh,chunk):
// Akk = K K^T (fp32, LDS), Bq = tril(Q K^T) incl diag (bf16 -> global, SWIZZLED),
// Dmat = (I + diag(b')*strictlow(Akk))^-1 diag(b')  (bf16 -> global, SWIZZLED).
// Kg/Qg are swizzled in global; fragment reads apply the same swizzle.
__global__ __launch_bounds__(64, 1) void precomp_kernel(
    const unsigned short* __restrict__ K16, const unsigned short* __restrict__ Q16,
    const float4* __restrict__ scal,
    unsigned short* __restrict__ Dg, unsigned short* __restrict__ Bg){
  __shared__ __align__(16) float sA[64*64];
  __shared__ float sbp[64];
  int inst = blockIdx.x;
  int bh = inst >> 5, ch = inst & 31;
  int ln = threadIdx.x, lm = ln & 15, quad = ln >> 4;
  const unsigned short* Kg = K16 + ((size_t)bh*SLEN + ch*CHK)*64;
  const unsigned short* Qg = Q16 + ((size_t)bh*SLEN + ch*CHK)*64;

  // Akk GEMM
  {
    f32x4 acc[4][4] = {};
    #pragma unroll
    for (int s = 0; s < 2; ++s){
      bf16x8 kf[4];
      #pragma unroll
      for (int i = 0; i < 4; ++i){
        int row = i*16+lm;
        kf[i] = *(const bf16x8*)(Kg + (size_t)row*64 + SWZ(row, s*32 + quad*8));
      }
      #pragma unroll
      for (int mi = 0; mi < 4; ++mi)
        #pragma unroll
        for (int ni = 0; ni < 4; ++ni)
          acc[mi][ni] = __builtin_amdgcn_mfma_f32_16x16x32_bf16(kf[mi], kf[ni], acc[mi][ni], 0, 0, 0);
    }
    #pragma unroll
    for (int mi = 0; mi < 4; ++mi)
      #pragma unroll
      for (int ni = 0; ni < 4; ++ni)
        #pragma unroll
        for (int rr = 0; rr < 4; ++rr)
          sA[(mi*16+quad*4+rr)*64 + ni*16+lm] = acc[mi][ni][rr];
  }
  sbp[ln] = scal[(size_t)bh*SLEN + ch*CHK + ln].x;
  __syncthreads();

  // Bq GEMM, masked swizzled store
  {
    f32x4 acc[4][4] = {};
    #pragma unroll
    for (int s = 0; s < 2; ++s){
      bf16x8 kf[4], qf[4];
      #pragma unroll
      for (int i = 0; i < 4; ++i){
        int row = i*16+lm;
        kf[i] = *(const bf16x8*)(Kg + (size_t)row*64 + SWZ(row, s*32 + quad*8));
        qf[i] = *(const bf16x8*)(Qg + (size_t)row*64 + SWZ(row, s*32 + quad*8));
      }
      #pragma unroll
      for (int mi = 0; mi < 4; ++mi)
        #pragma unroll
        for (int ni = 0; ni < 4; ++ni)
          acc[mi][ni] = __builtin_amdgcn_mfma_f32_16x16x32_bf16(qf[mi], kf[ni], acc[mi][ni], 0, 0, 0);
    }
    size_t io = (size_t)inst*4096;
    #pragma unroll
    for (int mi = 0; mi < 4; ++mi)
      #pragma unroll
      for (int ni = 0; ni < 4; ++ni)
        #pragma unroll
        for (int rr = 0; rr < 4; ++rr){
          int t = mi*16+quad*4+rr, j = ni*16+lm;
          float v = (j <= t) ? acc[mi][ni][rr] : 0.f;
          Bg[io + (size_t)t*64 + SWZ(t, j)] = f2bf(v);
        }
  }

  // triangular inversion: X = (I + diag(b')L)^-1 diag(b'); lane = column j
  {
    float x[64];
    x[0] = (ln == 0) ? sbp[0] : 0.f;
    #pragma unroll
    for (int i = 1; i < 64; ++i){
      float bi = sbp[i];
      float s = 0.f;
      #pragma unroll
      for (int m4 = 0; m4*4 < i; ++m4){
        float4 a = *(const float4*)&sA[i*64 + m4*4];
        if (m4*4+0 < i) s += a.x * x[m4*4+0];
        if (m4*4+1 < i) s += a.y * x[m4*4+1];
        if (m4*4+2 < i) s += a.z * x[m4*4+2];
        if (m4*4+3 < i) s += a.w * x[m4*4+3];
      }
      x[i] = ((ln == i) ? bi : 0.f) - bi*s;
    }
    size_t io = (size_t)inst*4096;
    #pragma unroll
    for (int i = 0; i < 64; ++i)
      Dg[io + (size_t)i*64 + SWZ(i, ln)] = f2bf(x[i]);
  }
}

// ------------------------------------------------------------------ chunked delta-rule, MFMA, r-split 8
// grid (64 bh, 8 rgroup); each block owns W rows r = rg*8..rg*8+7.
// MFMA operands keep 16-wide r (rows 8-15 garbage, outputs never stored: MFMA
// output col j depends only on B row j, so valid lanes are unpolluted).
// LDS = 79 KB -> 2 blocks/CU (8 waves/CU vs 4 before): one block's compute hides
// the other's barrier/vmcnt stalls. sV single-buffered; its next-chunk DMA is
// issued after the post-phase0 barrier (all V reads complete), landing is
// ordered by the next top-of-loop vmcnt(0).
__global__ __launch_bounds__(256, 2) void chunk_kernel(
    const unsigned short* __restrict__ K16, const unsigned short* __restrict__ Q16,
    const unsigned short* __restrict__ V16,
    const unsigned short* __restrict__ Dg, const unsigned short* __restrict__ Bg,
    const float4* __restrict__ scal, unsigned short* __restrict__ lo){
  __shared__ __align__(16) unsigned short sK[2][4096];   // K (t,d) swz
  __shared__ __align__(16) unsigned short sQ[2][4096];   // Q (t,d) swz
  __shared__ __align__(16) unsigned short sD[2][4096];   // D (t,j) swz
  __shared__ __align__(16) unsigned short sB[2][4096];   // Bq (t,j) swz
  __shared__ __align__(16) unsigned short sKT[4096];     // K^T (d,t) swz
  __shared__ __align__(16) unsigned short sV[512];       // V strip (t, 8r) linear, single-buf
  __shared__ __align__(16) unsigned short sX[1024];      // X^T (16r, t) swz (rows 8-15 garbage)
  __shared__ __align__(16) unsigned short sDT[1024];     // Delta^T (16r, t) swz (rows 8-15 garbage)
  __shared__ __align__(16) unsigned short sW[1024];      // W strip (16r, d) swz (rows 8-15 garbage)
  int bh = blockIdx.x, rg = blockIdx.y;
  int tid = threadIdx.x, wv = tid >> 6, ln = tid & 63, lm = ln & 15, quad = ln >> 4;
  size_t sb = (size_t)bh*SLEN*64;
  const unsigned short* Kg = K16 + sb;
  const unsigned short* Qg = Q16 + sb;
  const unsigned short* Vg = V16 + sb;
  const float4* scp = scal + (size_t)bh*SLEN;
  size_t lobase = (size_t)(bh>>4)*DMODEL + (size_t)(bh&15)*64 + rg*8;

  auto dma8 = [&](const unsigned short* g, unsigned short* s){
    #pragma unroll
    for (int it = 0; it < 2; ++it)
      gload_lds16(g + (wv*2+it)*512 + ln*8, s + (wv*2+it)*512);
  };
  auto dma_kqdb = [&](int ch, int p){
    size_t co = (size_t)ch*CHK*64;
    dma8(Kg + co, sK[p]);
    dma8(Qg + co, sQ[p]);
    size_t io = ((size_t)bh*NCH + ch)*4096;
    dma8(Dg + io, sD[p]);
    dma8(Bg + io, sB[p]);
  };
  auto dma_v = [&](int ch){
    if (wv == 0)
      gload_lds16(Vg + (size_t)ch*CHK*64 + (size_t)ln*64 + rg*8, sV);
  };
  auto frag = [&](const unsigned short* S, int row, int kb)->bf16x8 {
    return *(const bf16x8*)(S + row*64 + SWZ(row, kb));
  };

  if (tid < 128) ((uint4*)sW)[tid] = make_uint4(0u,0u,0u,0u);
  f32x4 Wacc = {0,0,0,0};
  dma_kqdb(0, 0);
  dma_v(0);

  for (int ch = 0; ch < NCH; ++ch){
    int p = ch & 1;
    const unsigned short* cK = sK[p];
    const unsigned short* cQ = sQ[p];
    const unsigned short* cD = sD[p];
    const unsigned short* cB = sB[p];
    int tb = ch*CHK + wv*16 + quad*4;
    float sz0 = scp[tb+0].z, sz1 = scp[tb+1].z, sz2 = scp[tb+2].z, sz3 = scp[tb+3].z;
    __builtin_amdgcn_s_waitcnt(0x0F70);   // vmcnt(0): this chunk's DMA (issued last chunk)
    __syncthreads();                      // publish buf p + sV + sW spills
    if (ch + 1 < NCH) dma_kqdb(ch + 1, p ^ 1);   // overlap next DMA with phases 0-2

    // phase0: M = K W^T, Mq = Q W^T (wave = t-tile wv)
    f32x4 Macc = {0,0,0,0}, Mqacc = {0,0,0,0};
    #pragma unroll
    for (int s = 0; s < 2; ++s){
      int kb = s*32 + quad*8;
      bf16x8 ak = frag(cK, wv*16+lm, kb);
      bf16x8 aq = frag(cQ, wv*16+lm, kb);
      bf16x8 bw = frag(sW, lm, kb);
      Macc  = __builtin_amdgcn_mfma_f32_16x16x32_bf16(ak, bw, Macc, 0, 0, 0);
      Mqacc = __builtin_amdgcn_mfma_f32_16x16x32_bf16(aq, bw, Mqacc, 0, 0, 0);
    }
    // K-transpose read: thread -> row t = ln, cols d0..d0+15 (d0 = wv*16)
    int d0 = wv*16;
    uint4 kr0 = *(const uint4*)(cK + ln*64 + SWZ(ln, d0));
    uint4 kr1 = *(const uint4*)(cK + ln*64 + SWZ(ln, d0+8));
    // X = V - M; scatter X^T into sX (cols lm>=8 read garbage, rows lm>=8 garbage)
    #pragma unroll
    for (int rr = 0; rr < 4; ++rr){
      int t = wv*16 + quad*4 + rr;
      float x = bf2f(sV[t*8 + (lm & 7)]) - Macc[rr];
      sX[lm*64 + SWZ(lm, t)] = f2bf(x);
    }
    // scatter K^T into sKT (per e: whole wave writes one row d)
    {
      const unsigned short* k0p = (const unsigned short*)&kr0;
      const unsigned short* k1p = (const unsigned short*)&kr1;
      #pragma unroll
      for (int e = 0; e < 8; ++e){
        int d = d0 + e;
        sKT[d*64 + SWZ(d, ln)] = k0p[e];
      }
      #pragma unroll
      for (int e = 0; e < 8; ++e){
        int d = d0 + 8 + e;
        sKT[d*64 + SWZ(d, ln)] = k1p[e];
      }
    }
    __syncthreads();   // sX, sKT ready; all sV reads done
    if (ch + 1 < NCH) dma_v(ch + 1);   // refill single-buffered sV

    // phase1: Delta[t,r] = D X  (A = D rows t, B = X^T rows r)
    f32x4 Dacc = {0,0,0,0};
    #pragma unroll
    for (int s = 0; s < 2; ++s){
      int kb = s*32 + quad*8;
      bf16x8 ad = frag(cD, wv*16+lm, kb);
      bf16x8 bx = frag(sX, lm, kb);
      Dacc = __builtin_amdgcn_mfma_f32_16x16x32_bf16(ad, bx, Dacc, 0, 0, 0);
    }
    #pragma unroll
    for (int rr = 0; rr < 4; ++rr){
      int t = wv*16 + quad*4 + rr;
      sDT[lm*64 + SWZ(lm, t)] = f2bf(Dacc[rr]);
    }
    __syncthreads();   // sDT ready

    // phase2: O = Mq + Bq Delta ; W += Delta^T K
    f32x4 Oacc = Mqacc;
    #pragma unroll
    for (int s = 0; s < 2; ++s){
      int kb = s*32 + quad*8;
      bf16x8 ab = frag(cB, wv*16+lm, kb);
      bf16x8 bd = frag(sDT, lm, kb);
      Oacc = __builtin_amdgcn_mfma_f32_16x16x32_bf16(ab, bd, Oacc, 0, 0, 0);
      bf16x8 adt = frag(sDT, lm, kb);
      bf16x8 bkt = frag(sKT, wv*16+lm, kb);
      Wacc = __builtin_amdgcn_mfma_f32_16x16x32_bf16(adt, bkt, Wacc, 0, 0, 0);
    }
    if (lm < 8){
      #pragma unroll
      for (int rr = 0; rr < 4; ++rr){
        int tabs = ch*CHK + wv*16 + quad*4 + rr;
        float sz = (rr==0)?sz0:(rr==1)?sz1:(rr==2)?sz2:sz3;
        lo[lobase + (size_t)tabs*(BSZ*DMODEL) + lm] = f2bf(Oacc[rr] * sz);
      }
    }
    // spill W strip (rows r = quad*4+rr, cols d = wv*16+lm); no barrier needed:
    // sW is only read in phase0, and the next top-of-loop barrier orders it.
    #pragma unroll
    for (int rr = 0; rr < 4; ++rr){
      int r = quad*4 + rr, d = wv*16 + lm;
      sW[r*64 + SWZ(r, d)] = f2bf(Wacc[rr]);
    }
  }
}

// ------------------------------------------------------------------ residual + layernorm (sums split-K partials)
__global__ __launch_bounds__(256) void ln_kernel(
    const float* __restrict__ hin, const float* __restrict__ a0,
    const float* __restrict__ a1,
    const float* __restrict__ g, const float* __restrict__ bta,
    float* __restrict__ out){
  int row = blockIdx.x, tid = threadIdx.x;
  size_t rb = (size_t)row * DMODEL;
  float4 hv = ((const float4*)(hin + rb))[tid];
  float4 v0 = ((const float4*)(a0 + rb))[tid];
  float4 v1 = ((const float4*)(a1 + rb))[tid];
  float4 x;
  x.x = hv.x + v0.x + v1.x; x.y = hv.y + v0.y + v1.y;
  x.z = hv.z + v0.z + v1.z; x.w = hv.w + v0.w + v1.w;
  float s  = x.x + x.y + x.z + x.w;
  float ss = x.x*x.x + x.y*x.y + x.z*x.z + x.w*x.w;
  #pragma unroll
  for (int off = 1; off < 64; off <<= 1){
    s  += __shfl_xor(s , off, 64);
    ss += __shfl_xor(ss, off, 64);
  }
  __shared__ float ls[4], lq[4];
  int wv = tid >> 6, ln = tid & 63;
  if (ln == 0){ ls[wv] = s; lq[wv] = ss; }
  __syncthreads();
  s  = ls[0] + ls[1] + ls[2] + ls[3];
  ss = lq[0] + lq[1] + lq[2] + lq[3];
  float mu  = s * (1.f/DMODEL);
  float var = ss * (1.f/DMODEL) - mu*mu;
  float rstd = rsqrtf(var + EPSV);
  float4 gv = ((const float4*)g)[tid], bv = ((const float4*)bta)[tid];
  float4 o;
  o.x = (x.x-mu)*rstd*gv.x + bv.x;
  o.y = (x.y-mu)*rstd*gv.y + bv.y;
  o.z = (x.z-mu)*rstd*gv.z + bv.z;
  o.w = (x.w-mu)*rstd*gv.w + bv.w;
  ((float4*)(out + rb))[tid] = o;
}

// ------------------------------------------------------------------ launch
// Workspace budget ~218 MB (ws overflow at ~251 MB killed rounds 3/4/7).
extern "C" void kernel_launch(void* const* d_in, const int* in_sizes, int n_in,
                              void* d_out, int out_size, void* d_ws, size_t ws_size,
                              hipStream_t stream){
  const float* h     = (const float*)d_in[0];
  const float* wqkvb = (const float*)d_in[1];
  const float* wo    = (const float*)d_in[2];
  const float* lng   = (const float*)d_in[3];
  const float* lnb   = (const float*)d_in[4];
  float* out = (float*)d_out;

  char* w = (char*)d_ws;
  auto take = [&](size_t bytes)->char*{
    char* p = w; w += (bytes + 255) & ~(size_t)255; return p;
  };
  unsigned short* h_bf    = (unsigned short*)take((size_t)MROWS*DMODEL*2);
  unsigned short* wq_bf   = (unsigned short*)take((size_t)NQPAD*DMODEL*2);
  unsigned short* wo_bf   = (unsigned short*)take((size_t)DMODEL*DMODEL*2);
  unsigned short* qkvb_bf = (unsigned short*)take((size_t)MROWS*NQPAD*2);
  float* attn1 = (float*)take((size_t)MROWS*DMODEL*4 + 4096);   // splitK partial 1
  float* Ab    = (float*)take((size_t)MROWS*DMODEL*4);   // aliased: D+Bq after scan_kden; attn0 after chunk
  float4* scal = (float4*)take((size_t)64*SLEN*16 + 4096);
  unsigned short* lo_bf = (unsigned short*)take((size_t)MROWS*DMODEL*2);
  float* Sseg = (float*)take((size_t)64*NSEG*64*4);
  unsigned short* kb16 = (unsigned short*)take((size_t)MROWS*DMODEL*2);
  unsigned short* qb16 = (unsigned short*)take((size_t)MROWS*DMODEL*2);
  unsigned short* vb16 = (unsigned short*)take((size_t)MROWS*DMODEL*2);
  unsigned short* Dg = (unsigned short*)Ab;
  unsigned short* Bg = (unsigned short*)Ab + (size_t)64*NCH*4096;
  float* attn0 = Ab;

  cast3_kernel<<<2048, 256, 0, stream>>>(h, h_bf, MROWS*DMODEL/4,
                                         wqkvb, wq_bf, NQKVB*DMODEL/4,
                                         wo, wo_bf, DMODEL*DMODEL/4);

  gemm8p_kernel<true, false><<<(MROWS/256)*(NQPAD/256), 512, 0, stream>>>(
      h_bf, wq_bf, qkvb_bf, nullptr, NQPAD, DMODEL, DMODEL, MROWS/256);

  segsum_kernel<<<dim3(64, NSEG), 64, 0, stream>>>(qkvb_bf, Sseg);
  scan_kden_kernel<<<dim3(64, NSEG), 64, 0, stream>>>(qkvb_bf, Sseg, qb16, vb16, kb16, scal);
  precomp_kernel<<<64*NCH, 64, 0, stream>>>(kb16, qb16, scal, Dg, Bg);
  chunk_kernel<<<dim3(64, 8), 256, 0, stream>>>(kb16, qb16, vb16, Dg, Bg, scal, lo_bf);

  // split-K=2: 256 blocks (full machine), halves write fp32 partials summed in ln
  gemm8p_kernel<false, true><<<2*(MROWS/256)*(DMODEL/256), 512, 0, stream>>>(
      lo_bf, wo_bf, attn0, attn1, DMODEL, DMODEL/2, DMODEL, MROWS/256);

  ln_kernel<<<MROWS, 256, 0, stream>>>(h, attn0, attn1, lng, lnb, out);
  (void)in_sizes; (void)n_in; (void)out_size; (void)ws_size;
}

// Round 10
// 367.353 us; speedup vs baseline: 1.0217x; 1.0217x over previous
//
#include <hip/hip_runtime.h>
#include <cstdint>
#include <cstddef>

#define D_HEAD   64
#define NHEAD    16
#define DMODEL   1024
#define SLEN     2048
#define BSZ      4
#define MROWS    (SLEN*BSZ)            // 8192
#define NQKVB    (NHEAD*(3*D_HEAD+1))  // 3088
#define NQPAD    3328                  // padded to 13*256 for the 256-tile GEMM
#define EPSV     1e-5f
#define SCALEV   0.125f                // 1/sqrt(64)
#define CHK      64                    // chunk length
#define NCH      (SLEN/CHK)            // 32

typedef short bf16x8 __attribute__((ext_vector_type(8)));
typedef float f32x4  __attribute__((ext_vector_type(4)));

__device__ __forceinline__ unsigned short f2bf(float f){
  unsigned int u = __float_as_uint(f);
  u = (u + 0x7fffu + ((u >> 16) & 1u)) >> 16;   // RNE
  return (unsigned short)u;
}
__device__ __forceinline__ float bf2f(unsigned short s){
  return __uint_as_float(((unsigned int)s) << 16);
}

__device__ __forceinline__ void gload_lds16(const unsigned short* g, unsigned short* l){
  __builtin_amdgcn_global_load_lds((const __attribute__((address_space(1))) void*)g,
                                   (__attribute__((address_space(3))) void*)l, 16, 0, 0);
}

// swizzled in-row offset: XOR the 8-element block index with (row&7)
#define SWZ(row, col) ((col) ^ (((row)&7)<<3))

// ------------------------------------------------------------------ fused casts
__global__ void cast3_kernel(const float* __restrict__ s0, unsigned short* __restrict__ d0, int n0,
                             const float* __restrict__ s1, unsigned short* __restrict__ d1, int n1,
                             const float* __restrict__ s2, unsigned short* __restrict__ d2, int n2){
  int total = n0 + n1 + n2;
  int stride = gridDim.x * blockDim.x;
  for (int i = blockIdx.x*blockDim.x + threadIdx.x; i < total; i += stride){
    const float* s; unsigned short* d; int j = i;
    if (j < n0){ s = s0; d = d0; }
    else if (j < n0 + n1){ j -= n0; s = s1; d = d1; }
    else { j -= n0 + n1; s = s2; d = d2; }
    float4 f = ((const float4*)s)[j];
    ushort4 u;
    u.x = f2bf(f.x); u.y = f2bf(f.y); u.z = f2bf(f.z); u.w = f2bf(f.w);
    ((ushort4*)d)[j] = u;
  }
}

// ------------------------------------------------------------------ GEMM (NT), 256x256 8-phase template
// BM=BN=256, BK=64, 8 waves (2M x 4N), 512 threads, 128 KiB LDS double-buffer.
// LDS tiles XOR-swizzled via pre-swizzled global SOURCE; reads apply the same XOR.
// Counted vmcnt(2) at phases 4/8. 2D-chunked XCD mapping keeps each XCD's A slab
// L2-resident (FETCH 123->47 MB measured r6); kernel is schedule-bound at ~28%
// MfmaUtil, consistent with the template ceiling at K=1024 / 1.625-round grids.
// SPLITK: first/second half of the grid computes K/2 depth into C/C2 (fp32).
#define GBAR  do{ asm volatile("" ::: "memory"); __builtin_amdgcn_s_barrier(); asm volatile("" ::: "memory"); }while(0)
#define WVM2  asm volatile("s_waitcnt vmcnt(2)" ::: "memory")
#define WLG0  asm volatile("s_waitcnt lgkmcnt(0)" ::: "memory")
#define WLG8  asm volatile("s_waitcnt lgkmcnt(8)" ::: "memory")

#define LDA(sb_, mih_) do{ \
  _Pragma("unroll") \
  for (int m2 = 0; m2 < 4; ++m2) \
    _Pragma("unroll") \
    for (int ks = 0; ks < 2; ++ks) \
      aF[m2][ks] = frag(sb_, wmi*128 + (mih_)*64 + m2*16 + lm, ks); \
}while(0)

#define LDB(sb_, nih_) do{ \
  _Pragma("unroll") \
  for (int n2 = 0; n2 < 2; ++n2) \
    _Pragma("unroll") \
    for (int ks = 0; ks < 2; ++ks) \
      bF[(nih_)*2+n2][ks] = frag(sb_, wni*64 + (nih_)*32 + n2*16 + lm, ks); \
}while(0)

#define MMA(mih_, nih_) do{ \
  __builtin_amdgcn_s_setprio(1); \
  _Pragma("unroll") \
  for (int m2 = 0; m2 < 4; ++m2) \
    _Pragma("unroll") \
    for (int n2 = 0; n2 < 2; ++n2) \
      _Pragma("unroll") \
      for (int ks = 0; ks < 2; ++ks) \
        acc[(mih_)*4+m2][(nih_)*2+n2] = __builtin_amdgcn_mfma_f32_16x16x32_bf16( \
            aF[m2][ks], bF[(nih_)*2+n2][ks], acc[(mih_)*4+m2][(nih_)*2+n2], 0, 0, 0); \
  __builtin_amdgcn_s_setprio(0); \
}while(0)

template<bool OUT_BF16, bool SPLITK>
__global__ __launch_bounds__(512, 2) void gemm8p_kernel(
    const unsigned short* __restrict__ A, const unsigned short* __restrict__ B,
    void* __restrict__ C, void* __restrict__ C2, int N, int K, int lda, int tm){
  __shared__ __align__(16) unsigned short sA[2][256*64];
  __shared__ __align__(16) unsigned short sB[2][256*64];
  int tid = threadIdx.x;
  int wv = tid >> 6, ln = tid & 63, lm = ln & 15, quad = ln >> 4;
  // 2D-chunked bijective XCD mapping (requires tm%8==0; grid%8==0):
  //   xcd = wg&7 owns bm in [xcd*CM, (xcd+1)*CM), bn-major walk.
  int wg = blockIdx.x;
  int kh = 0;
  if (SPLITK){ int half = gridDim.x >> 1; if (wg >= half){ kh = 1; wg -= half; } }
  int xcd = wg & 7, l = wg >> 3;
  int CM = tm >> 3;
  int bn = l / CM, bm = xcd*CM + (l - bn*CM);
  int m0 = bm << 8, n0 = bn << 8;
  int wmi = wv >> 2, wni = wv & 3;
  const unsigned short* Ag = A + (size_t)m0*lda + (size_t)kh*K;
  const unsigned short* Bg = B + (size_t)n0*lda + (size_t)kh*K;

  f32x4 acc[8][4] = {};
  bf16x8 aF[4][2], bF[4][2];

  // iteration-invariant staging geometry: round r covers linear elem-blocks
  // e = r*512 + wv*64 + ln ; row = e>>3 ; cb = e&7 ; source col-block inverse-swizzled.
  int e0 = wv*64 + ln;
  int r0row = e0 >> 3, r0cb = e0 & 7;
  int e1 = 512 + e0;
  int r1row = e1 >> 3, r1cb = e1 & 7;
  size_t gsrc0 = (size_t)r0row*lda + ((r0cb ^ (r0row & 7)) << 3);
  size_t gsrc1 = (size_t)r1row*lda + ((r1cb ^ (r1row & 7)) << 3);
  int ldst0 = (wv*64) * 8;           // wave-uniform LDS elem offsets
  int ldst1 = (512 + wv*64) * 8;

  auto stage = [&](const unsigned short* g, unsigned short* sb, int h, int kt){
    gload_lds16(g + (size_t)h*128*lda + kt + gsrc0, sb + h*8192 + ldst0);
    gload_lds16(g + (size_t)h*128*lda + kt + gsrc1, sb + h*8192 + ldst1);
  };
  auto frag = [&](const unsigned short* sb, int row, int ks)->bf16x8 {
    return *(const bf16x8*)(sb + row*64 + ((((ks<<2)+quad) ^ (row & 7)) << 3));
  };

  // prologue: tile0 -> buf0 (4 half-tiles), tile1 A-h0 -> buf1; publish tile0.
  stage(Ag, sA[0], 0, 0);
  stage(Ag, sA[0], 1, 0);
  stage(Bg, sB[0], 0, 0);
  stage(Bg, sB[0], 1, 0);
  stage(Ag, sA[1], 0, 64);
  WVM2;
  GBAR;

  int nit = K >> 7;                   // 2 K-tiles (BK=64) per iteration
  for (int i = 0; i < nit; ++i){
    int k1 = (i<<7) + 64;             // odd tile of this iteration
    int k2 = ((i<<7) + 128) & (K-1);  // next even tile (wraps harmlessly at end)
    int k3 = ((i<<7) + 192) & (K-1);  // next odd tile

    // phase 1: Q(mi0-3 x ni0-1) on buf0
    LDA(sA[0], 0); LDB(sB[0], 0);
    stage(Ag, sA[1], 1, k1);
    WLG8;
    GBAR; WLG0; MMA(0,0); GBAR;
    // phase 2: Q(mi0-3 x ni2-3)
    LDB(sB[0], 1);
    stage(Bg, sB[1], 0, k1);
    GBAR; WLG0; MMA(0,1); GBAR;
    // phase 3: Q(mi4-7 x ni0-1)
    LDA(sA[0], 1);
    stage(Bg, sB[1], 1, k1);
    GBAR; WLG0; MMA(1,0); GBAR;
    // phase 4: Q(mi4-7 x ni2-3); publish buf1
    stage(Ag, sA[0], 0, k2);
    GBAR; MMA(1,1); WVM2; GBAR;
    // phase 5: buf1
    LDA(sA[1], 0); LDB(sB[1], 0);
    stage(Ag, sA[0], 1, k2);
    WLG8;
    GBAR; WLG0; MMA(0,0); GBAR;
    // phase 6
    LDB(sB[1], 1);
    stage(Bg, sB[0], 0, k2);
    GBAR; WLG0; MMA(0,1); GBAR;
    // phase 7
    LDA(sA[1], 1);
    stage(Bg, sB[0], 1, k2);
    GBAR; WLG0; MMA(1,0); GBAR;
    // phase 8: publish buf0 (next even tile)
    stage(Ag, sA[1], 0, k3);
    GBAR; MMA(1,1); WVM2; GBAR;
  }
  asm volatile("s_waitcnt vmcnt(0)" ::: "memory");  // drain trailing LDS-DMA before exit

  float* Cf = (float*)((SPLITK && kh) ? C2 : C);
  #pragma unroll
  for (int mi = 0; mi < 8; ++mi){
    int rowm = m0 + wmi*128 + mi*16 + quad*4;
    #pragma unroll
    for (int ni = 0; ni < 4; ++ni){
      int col = n0 + wni*64 + ni*16 + lm;
      size_t cb = (size_t)rowm * N + col;
      #pragma unroll
      for (int rr = 0; rr < 4; ++rr){
        float v = acc[mi][ni][rr];
        if (OUT_BF16) ((unsigned short*)C)[cb + (size_t)rr*N] = f2bf(v);
        else          Cf[cb + (size_t)rr*N] = v;
      }
    }
  }
}

#undef LDA
#undef LDB
#undef MMA
#undef GBAR
#undef WVM2
#undef WLG0
#undef WLG8

// ------------------------------------------------------------------ segmented cumsum over l
// NSEG=64 (SEGL=32): 4096 waves -> 16 waves/CU for the serial latency chains.
// kn is RECOMPUTED from qkvb_bf (bit-exact vs the old prep path: same bf16 inputs,
// same expf, same shuffle order) — kills the kb fp32 round-trip entirely.
#define NSEG 64
#define SEGL (SLEN/NSEG)   // 32
__global__ __launch_bounds__(64) void segsum_kernel(
    const unsigned short* __restrict__ qkvb, float* __restrict__ S){
  int bh = blockIdx.x, seg = blockIdx.y, ln = threadIdx.x;
  int b = bh >> 4, h = bh & 15;
  float s = 0.f;
  for (int i = 0; i < SEGL; ++i){
    int t = seg*SEGL + i;
    size_t rb = (size_t)(t*4+b) * NQPAD + (size_t)h*193;
    float kr = bf2f(qkvb[rb + 64 + ln]);
    float k1 = kr > 0.f ? kr + 1.f : __expf(kr);   // elu(x)+1
    float sk = k1;
    #pragma unroll
    for (int off = 1; off < 64; off <<= 1) sk += __shfl_xor(sk, off, 64);
    s += k1 / sk;
  }
  S[((size_t)bh*NSEG + seg)*64 + ln] = s;
}

// ------------------------------------------------------------------ fused prep + scan + denominators
// Recomputes qn/kn from qkvb_bf (bit-exact vs old prep), walks the inclusive
// cumsum, computes the three denominator reductions, and writes ALL downstream
// inputs: qb16/vb16 (bf16), kb16 (normalized bf16, swizzled), scal.
__global__ __launch_bounds__(64) void scan_kden_kernel(
    const unsigned short* __restrict__ qkvb, const float* __restrict__ S,
    unsigned short* __restrict__ qb16, unsigned short* __restrict__ vb16,
    unsigned short* __restrict__ kb16, float4* __restrict__ scal){
  int bh = blockIdx.x, seg = blockIdx.y, ln = threadIdx.x;
  int b = bh >> 4, h = bh & 15;
  float acc = 0.f;
  for (int s = 0; s < seg; ++s) acc += S[((size_t)bh*NSEG + s)*64 + ln];
  for (int i = 0; i < SEGL; ++i){
    int t = seg*SEGL + i;
    size_t rb = (size_t)(t*4+b) * NQPAD + (size_t)h*193;
    float qr = bf2f(qkvb[rb + ln]);
    float kr = bf2f(qkvb[rb + 64 + ln]);
    float vr = bf2f(qkvb[rb + 128 + ln]);
    float q1 = qr > 0.f ? qr + 1.f : __expf(qr);   // elu(x)+1
    float k1 = kr > 0.f ? kr + 1.f : __expf(kr);
    float sq = q1, sk = k1;
    #pragma unroll
    for (int off = 1; off < 64; off <<= 1){
      sq += __shfl_xor(sq, off, 64);
      sk += __shfl_xor(sk, off, 64);
    }
    float qn = q1 / sq, kn = k1 / sk;
    acc += kn;
    float a = acc;
    float d0 = (a - kn)*kn, d1 = a*qn, d2 = kn*qn;
    #pragma unroll
    for (int off = 1; off < 64; off <<= 1){
      d0 += __shfl_xor(d0, off, 64);
      d1 += __shfl_xor(d1, off, 64);
      d2 += __shfl_xor(d2, off, 64);
    }
    float kd  = (t == 0) ? 1.f : d0;
    float inv = 1.f / (kd + EPSV);
    float kf = kn * inv;
    size_t row = ((size_t)bh*SLEN + t)*64;
    qb16[row + SWZ(t, ln)] = f2bf(qn);
    vb16[row + ln] = f2bf(vr);
    kb16[row + SWZ(t, ln)] = f2bf(kf);
    if (ln == 0){
      float br = bf2f(qkvb[rb + 192]);
      float sb = 1.f / (1.f + __expf(-br));
      scal[(size_t)bh*SLEN + t] = make_float4(sb * kd, d2 * inv, SCALEV/(d1 + EPSV), 0.f);
    }
  }
}

// ------------------------------------------------------------------ precompute per (bh,chunk):
// Akk = K K^T (fp32, LDS), Bq = tril(Q K^T) incl diag (bf16 -> global, SWIZZLED),
// Dmat = (I + diag(b')*strictlow(Akk))^-1 diag(b')  (bf16 -> global, SWIZZLED).
// Kg/Qg are swizzled in global; fragment reads apply the same swizzle.
__global__ __launch_bounds__(64, 1) void precomp_kernel(
    const unsigned short* __restrict__ K16, const unsigned short* __restrict__ Q16,
    const float4* __restrict__ scal,
    unsigned short* __restrict__ Dg, unsigned short* __restrict__ Bg){
  __shared__ __align__(16) float sA[64*64];
  __shared__ float sbp[64];
  int inst = blockIdx.x;
  int bh = inst >> 5, ch = inst & 31;
  int ln = threadIdx.x, lm = ln & 15, quad = ln >> 4;
  const unsigned short* Kg = K16 + ((size_t)bh*SLEN + ch*CHK)*64;
  const unsigned short* Qg = Q16 + ((size_t)bh*SLEN + ch*CHK)*64;

  // Akk GEMM
  {
    f32x4 acc[4][4] = {};
    #pragma unroll
    for (int s = 0; s < 2; ++s){
      bf16x8 kf[4];
      #pragma unroll
      for (int i = 0; i < 4; ++i){
        int row = i*16+lm;
        kf[i] = *(const bf16x8*)(Kg + (size_t)row*64 + SWZ(row, s*32 + quad*8));
      }
      #pragma unroll
      for (int mi = 0; mi < 4; ++mi)
        #pragma unroll
        for (int ni = 0; ni < 4; ++ni)
          acc[mi][ni] = __builtin_amdgcn_mfma_f32_16x16x32_bf16(kf[mi], kf[ni], acc[mi][ni], 0, 0, 0);
    }
    #pragma unroll
    for (int mi = 0; mi < 4; ++mi)
      #pragma unroll
      for (int ni = 0; ni < 4; ++ni)
        #pragma unroll
        for (int rr = 0; rr < 4; ++rr)
          sA[(mi*16+quad*4+rr)*64 + ni*16+lm] = acc[mi][ni][rr];
  }
  sbp[ln] = scal[(size_t)bh*SLEN + ch*CHK + ln].x;
  __syncthreads();

  // Bq GEMM, masked swizzled store
  {
    f32x4 acc[4][4] = {};
    #pragma unroll
    for (int s = 0; s < 2; ++s){
      bf16x8 kf[4], qf[4];
      #pragma unroll
      for (int i = 0; i < 4; ++i){
        int row = i*16+lm;
        kf[i] = *(const bf16x8*)(Kg + (size_t)row*64 + SWZ(row, s*32 + quad*8));
        qf[i] = *(const bf16x8*)(Qg + (size_t)row*64 + SWZ(row, s*32 + quad*8));
      }
      #pragma unroll
      for (int mi = 0; mi < 4; ++mi)
        #pragma unroll
        for (int ni = 0; ni < 4; ++ni)
          acc[mi][ni] = __builtin_amdgcn_mfma_f32_16x16x32_bf16(qf[mi], kf[ni], acc[mi][ni], 0, 0, 0);
    }
    size_t io = (size_t)inst*4096;
    #pragma unroll
    for (int mi = 0; mi < 4; ++mi)
      #pragma unroll
      for (int ni = 0; ni < 4; ++ni)
        #pragma unroll
        for (int rr = 0; rr < 4; ++rr){
          int t = mi*16+quad*4+rr, j = ni*16+lm;
          float v = (j <= t) ? acc[mi][ni][rr] : 0.f;
          Bg[io + (size_t)t*64 + SWZ(t, j)] = f2bf(v);
        }
  }

  // triangular inversion: X = (I + diag(b')L)^-1 diag(b'); lane = column j
  {
    float x[64];
    x[0] = (ln == 0) ? sbp[0] : 0.f;
    #pragma unroll
    for (int i = 1; i < 64; ++i){
      float bi = sbp[i];
      float s = 0.f;
      #pragma unroll
      for (int m4 = 0; m4*4 < i; ++m4){
        float4 a = *(const float4*)&sA[i*64 + m4*4];
        if (m4*4+0 < i) s += a.x * x[m4*4+0];
        if (m4*4+1 < i) s += a.y * x[m4*4+1];
        if (m4*4+2 < i) s += a.z * x[m4*4+2];
        if (m4*4+3 < i) s += a.w * x[m4*4+3];
      }
      x[i] = ((ln == i) ? bi : 0.f) - bi*s;
    }
    size_t io = (size_t)inst*4096;
    #pragma unroll
    for (int i = 0; i < 64; ++i)
      Dg[io + (size_t)i*64 + SWZ(i, ln)] = f2bf(x[i]);
  }
}

// ------------------------------------------------------------------ chunked delta-rule, MFMA, r-split 4, 2 blocks/CU
// grid (64 bh, 4 rgroup); each block owns W rows r = rg*16..rg*16+15.
// LDS cut 82->74 KB by single-buffering sB1 (Bq, consumed only in phase2): its
// next-chunk DMA issues after a post-phase2 barrier (all reads complete), landing
// ordered by the next loop-top vmcnt(0). 74KB*2 = 148 <= 160 KB -> 2 blocks/CU:
// the co-resident block's compute hides this block's barrier/vmcnt stalls.
__global__ __launch_bounds__(256, 2) void chunk_kernel(
    const unsigned short* __restrict__ K16, const unsigned short* __restrict__ Q16,
    const unsigned short* __restrict__ V16,
    const unsigned short* __restrict__ Dg, const unsigned short* __restrict__ Bg,
    const float4* __restrict__ scal, unsigned short* __restrict__ lo){
  __shared__ __align__(16) unsigned short sK[2][4096];   // K (t,d) swz
  __shared__ __align__(16) unsigned short sQ[2][4096];   // Q (t,d) swz
  __shared__ __align__(16) unsigned short sD[2][4096];   // D (t,j) swz
  __shared__ __align__(16) unsigned short sB1[4096];     // Bq (t,j) swz, single-buf
  __shared__ __align__(16) unsigned short sKT[4096];     // K^T (d,t) swz
  __shared__ __align__(16) unsigned short sV[2][1024];   // V strip (t, 16r) linear
  __shared__ __align__(16) unsigned short sX[1024];      // X^T (16r, t) swz
  __shared__ __align__(16) unsigned short sDT[1024];     // Delta^T (16r, t) swz
  __shared__ __align__(16) unsigned short sW[1024];      // W strip (16r, d) swz
  int bh = blockIdx.x, rg = blockIdx.y;
  int tid = threadIdx.x, wv = tid >> 6, ln = tid & 63, lm = ln & 15, quad = ln >> 4;
  size_t sb = (size_t)bh*SLEN*64;
  const unsigned short* Kg = K16 + sb;
  const unsigned short* Qg = Q16 + sb;
  const unsigned short* Vg = V16 + sb;
  const float4* scp = scal + (size_t)bh*SLEN;
  size_t lobase = (size_t)(bh>>4)*DMODEL + (size_t)(bh&15)*64 + rg*16;

  auto dma8 = [&](const unsigned short* g, unsigned short* s){
    #pragma unroll
    for (int it = 0; it < 2; ++it)
      gload_lds16(g + (wv*2+it)*512 + ln*8, s + (wv*2+it)*512);
  };
  auto dma_kqdv = [&](int ch, int p){
    size_t co = (size_t)ch*CHK*64;
    dma8(Kg + co, sK[p]);
    dma8(Qg + co, sQ[p]);
    dma8(Dg + ((size_t)bh*NCH + ch)*4096, sD[p]);
    if (wv == 0){
      gload_lds16(Vg + co + (size_t)(ln>>1)*64 + rg*16 + (ln&1)*8, sV[p]);
      gload_lds16(Vg + co + (size_t)(32 + (ln>>1))*64 + rg*16 + (ln&1)*8, sV[p] + 512);
    }
  };
  auto dma_b = [&](int ch){
    dma8(Bg + ((size_t)bh*NCH + ch)*4096, sB1);
  };
  auto frag = [&](const unsigned short* S, int row, int kb)->bf16x8 {
    return *(const bf16x8*)(S + row*64 + SWZ(row, kb));
  };

  if (tid < 128) ((uint4*)sW)[tid] = make_uint4(0u,0u,0u,0u);
  f32x4 Wacc = {0,0,0,0};
  dma_kqdv(0, 0);
  dma_b(0);

  for (int ch = 0; ch < NCH; ++ch){
    int p = ch & 1;
    const unsigned short* cK = sK[p];
    const unsigned short* cQ = sQ[p];
    const unsigned short* cD = sD[p];
    const unsigned short* cV = sV[p];
    int tb = ch*CHK + wv*16 + quad*4;
    float sz0 = scp[tb+0].z, sz1 = scp[tb+1].z, sz2 = scp[tb+2].z, sz3 = scp[tb+3].z;
    __builtin_amdgcn_s_waitcnt(0x0F70);   // vmcnt(0): this chunk's DMA (incl. late B)
    __syncthreads();                      // publish buf p + sB1 + sW spills
    if (ch + 1 < NCH) dma_kqdv(ch + 1, p ^ 1);   // overlap next K/Q/D/V DMA with phases 0-2

    // phase0: M = K W^T, Mq = Q W^T (wave = t-tile wv)
    f32x4 Macc = {0,0,0,0}, Mqacc = {0,0,0,0};
    #pragma unroll
    for (int s = 0; s < 2; ++s){
      int kb = s*32 + quad*8;
      bf16x8 ak = frag(cK, wv*16+lm, kb);
      bf16x8 aq = frag(cQ, wv*16+lm, kb);
      bf16x8 bw = frag(sW, lm, kb);
      Macc  = __builtin_amdgcn_mfma_f32_16x16x32_bf16(ak, bw, Macc, 0, 0, 0);
      Mqacc = __builtin_amdgcn_mfma_f32_16x16x32_bf16(aq, bw, Mqacc, 0, 0, 0);
    }
    // K-transpose read: thread -> row t = ln, cols d0..d0+15 (d0 = wv*16)
    int d0 = wv*16;
    uint4 kr0 = *(const uint4*)(cK + ln*64 + SWZ(ln, d0));
    uint4 kr1 = *(const uint4*)(cK + ln*64 + SWZ(ln, d0+8));
    // X = V - M; scatter X^T into sX
    #pragma unroll
    for (int rr = 0; rr < 4; ++rr){
      int t = wv*16 + quad*4 + rr;
      float x = bf2f(cV[t*16 + lm]) - Macc[rr];
      sX[lm*64 + SWZ(lm, t)] = f2bf(x);
    }
    // scatter K^T into sKT (per e: whole wave writes one row d)
    {
      const unsigned short* k0p = (const unsigned short*)&kr0;
      const unsigned short* k1p = (const unsigned short*)&kr1;
      #pragma unroll
      for (int e = 0; e < 8; ++e){
        int d = d0 + e;
        sKT[d*64 + SWZ(d, ln)] = k0p[e];
      }
      #pragma unroll
      for (int e = 0; e < 8; ++e){
        int d = d0 + 8 + e;
        sKT[d*64 + SWZ(d, ln)] = k1p[e];
      }
    }
    __syncthreads();   // sX, sKT ready

    // phase1: Delta[t,r] = D X  (A = D rows t, B = X^T rows r)
    f32x4 Dacc = {0,0,0,0};
    #pragma unroll
    for (int s = 0; s < 2; ++s){
      int kb = s*32 + quad*8;
      bf16x8 ad = frag(cD, wv*16+lm, kb);
      bf16x8 bx = frag(sX, lm, kb);
      Dacc = __builtin_amdgcn_mfma_f32_16x16x32_bf16(ad, bx, Dacc, 0, 0, 0);
    }
    #pragma unroll
    for (int rr = 0; rr < 4; ++rr){
      int t = wv*16 + quad*4 + rr;
      sDT[lm*64 + SWZ(lm, t)] = f2bf(Dacc[rr]);
    }
    __syncthreads();   // sDT ready

    // phase2: O = Mq + Bq Delta ; W += Delta^T K
    f32x4 Oacc = Mqacc;
    #pragma unroll
    for (int s = 0; s < 2; ++s){
      int kb = s*32 + quad*8;
      bf16x8 ab = frag(sB1, wv*16+lm, kb);
      bf16x8 bd = frag(sDT, lm, kb);
      Oacc = __builtin_amdgcn_mfma_f32_16x16x32_bf16(ab, bd, Oacc, 0, 0, 0);
      bf16x8 adt = frag(sDT, lm, kb);
      bf16x8 bkt = frag(sKT, wv*16+lm, kb);
      Wacc = __builtin_amdgcn_mfma_f32_16x16x32_bf16(adt, bkt, Wacc, 0, 0, 0);
    }
    #pragma unroll
    for (int rr = 0; rr < 4; ++rr){
      int tabs = ch*CHK + wv*16 + quad*4 + rr;
      float sz = (rr==0)?sz0:(rr==1)?sz1:(rr==2)?sz2:sz3;
      lo[lobase + (size_t)tabs*(BSZ*DMODEL) + lm] = f2bf(Oacc[rr] * sz);
    }
    __syncthreads();   // all sB1 (and phase2 LDS) reads of this chunk done
    if (ch + 1 < NCH) dma_b(ch + 1);   // refill single-buffered sB1
    // spill W strip (rows r = quad*4+rr, cols d = wv*16+lm); next loop-top
    // barrier orders these writes before phase0's sW reads.
    #pragma unroll
    for (int rr = 0; rr < 4; ++rr){
      int r = quad*4 + rr, d = wv*16 + lm;
      sW[r*64 + SWZ(r, d)] = f2bf(Wacc[rr]);
    }
  }
}

// ------------------------------------------------------------------ residual + layernorm (sums split-K partials)
__global__ __launch_bounds__(256) void ln_kernel(
    const float* __restrict__ hin, const float* __restrict__ a0,
    const float* __restrict__ a1,
    const float* __restrict__ g, const float* __restrict__ bta,
    float* __restrict__ out){
  int row = blockIdx.x, tid = threadIdx.x;
  size_t rb = (size_t)row * DMODEL;
  float4 hv = ((const float4*)(hin + rb))[tid];
  float4 v0 = ((const float4*)(a0 + rb))[tid];
  float4 v1 = ((const float4*)(a1 + rb))[tid];
  float4 x;
  x.x = hv.x + v0.x + v1.x; x.y = hv.y + v0.y + v1.y;
  x.z = hv.z + v0.z + v1.z; x.w = hv.w + v0.w + v1.w;
  float s  = x.x + x.y + x.z + x.w;
  float ss = x.x*x.x + x.y*x.y + x.z*x.z + x.w*x.w;
  #pragma unroll
  for (int off = 1; off < 64; off <<= 1){
    s  += __shfl_xor(s , off, 64);
    ss += __shfl_xor(ss, off, 64);
  }
  __shared__ float ls[4], lq[4];
  int wv = tid >> 6, ln = tid & 63;
  if (ln == 0){ ls[wv] = s; lq[wv] = ss; }
  __syncthreads();
  s  = ls[0] + ls[1] + ls[2] + ls[3];
  ss = lq[0] + lq[1] + lq[2] + lq[3];
  float mu  = s * (1.f/DMODEL);
  float var = ss * (1.f/DMODEL) - mu*mu;
  float rstd = rsqrtf(var + EPSV);
  float4 gv = ((const float4*)g)[tid], bv = ((const float4*)bta)[tid];
  float4 o;
  o.x = (x.x-mu)*rstd*gv.x + bv.x;
  o.y = (x.y-mu)*rstd*gv.y + bv.y;
  o.z = (x.z-mu)*rstd*gv.z + bv.z;
  o.w = (x.w-mu)*rstd*gv.w + bv.w;
  ((float4*)(out + rb))[tid] = o;
}

// ------------------------------------------------------------------ launch
// Workspace budget ~218 MB (ws overflow at ~251 MB killed rounds 3/4/7).
extern "C" void kernel_launch(void* const* d_in, const int* in_sizes, int n_in,
                              void* d_out, int out_size, void* d_ws, size_t ws_size,
                              hipStream_t stream){
  const float* h     = (const float*)d_in[0];
  const float* wqkvb = (const float*)d_in[1];
  const float* wo    = (const float*)d_in[2];
  const float* lng   = (const float*)d_in[3];
  const float* lnb   = (const float*)d_in[4];
  float* out = (float*)d_out;

  char* w = (char*)d_ws;
  auto take = [&](size_t bytes)->char*{
    char* p = w; w += (bytes + 255) & ~(size_t)255; return p;
  };
  unsigned short* h_bf    = (unsigned short*)take((size_t)MROWS*DMODEL*2);
  unsigned short* wq_bf   = (unsigned short*)take((size_t)NQPAD*DMODEL*2);
  unsigned short* wo_bf   = (unsigned short*)take((size_t)DMODEL*DMODEL*2);
  unsigned short* qkvb_bf = (unsigned short*)take((size_t)MROWS*NQPAD*2);
  float* attn1 = (float*)take((size_t)MROWS*DMODEL*4 + 4096);   // splitK partial 1
  float* Ab    = (float*)take((size_t)MROWS*DMODEL*4);   // aliased: D+Bq after scan_kden; attn0 after chunk
  float4* scal = (float4*)take((size_t)64*SLEN*16 + 4096);
  unsigned short* lo_bf = (unsigned short*)take((size_t)MROWS*DMODEL*2);
  float* Sseg = (float*)take((size_t)64*NSEG*64*4);
  unsigned short* kb16 = (unsigned short*)take((size_t)MROWS*DMODEL*2);
  unsigned short* qb16 = (unsigned short*)take((size_t)MROWS*DMODEL*2);
  unsigned short* vb16 = (unsigned short*)take((size_t)MROWS*DMODEL*2);
  unsigned short* Dg = (unsigned short*)Ab;
  unsigned short* Bg = (unsigned short*)Ab + (size_t)64*NCH*4096;
  float* attn0 = Ab;

  cast3_kernel<<<2048, 256, 0, stream>>>(h, h_bf, MROWS*DMODEL/4,
                                         wqkvb, wq_bf, NQKVB*DMODEL/4,
                                         wo, wo_bf, DMODEL*DMODEL/4);

  gemm8p_kernel<true, false><<<(MROWS/256)*(NQPAD/256), 512, 0, stream>>>(
      h_bf, wq_bf, qkvb_bf, nullptr, NQPAD, DMODEL, DMODEL, MROWS/256);

  segsum_kernel<<<dim3(64, NSEG), 64, 0, stream>>>(qkvb_bf, Sseg);
  scan_kden_kernel<<<dim3(64, NSEG), 64, 0, stream>>>(qkvb_bf, Sseg, qb16, vb16, kb16, scal);
  precomp_kernel<<<64*NCH, 64, 0, stream>>>(kb16, qb16, scal, Dg, Bg);
  chunk_kernel<<<dim3(64, 4), 256, 0, stream>>>(kb16, qb16, vb16, Dg, Bg, scal, lo_bf);

  // split-K=2: 256 blocks (full machine), halves write fp32 partials summed in ln
  gemm8p_kernel<false, true><<<2*(MROWS/256)*(DMODEL/256), 512, 0, stream>>>(
      lo_bf, wo_bf, attn0, attn1, DMODEL, DMODEL/2, DMODEL, MROWS/256);

  ln_kernel<<<MROWS, 256, 0, stream>>>(h, attn0, attn1, lng, lnb, out);
  (void)in_sizes; (void)n_in; (void)out_size; (void)ws_size;
}

// Round 11
// 362.463 us; speedup vs baseline: 1.0355x; 1.0135x over previous
//
#include <hip/hip_runtime.h>
#include <cstdint>
#include <cstddef>

#define D_HEAD   64
#define NHEAD    16
#define DMODEL   1024
#define SLEN     2048
#define BSZ      4
#define MROWS    (SLEN*BSZ)            // 8192
#define NQKVB    (NHEAD*(3*D_HEAD+1))  // 3088
#define NQPAD    3328                  // padded to 13*256 for the 256-tile GEMM
#define EPSV     1e-5f
#define SCALEV   0.125f                // 1/sqrt(64)
#define CHK      64                    // chunk length
#define NCH      (SLEN/CHK)            // 32

typedef short bf16x8 __attribute__((ext_vector_type(8)));
typedef float f32x4  __attribute__((ext_vector_type(4)));

__device__ __forceinline__ unsigned short f2bf(float f){
  unsigned int u = __float_as_uint(f);
  u = (u + 0x7fffu + ((u >> 16) & 1u)) >> 16;   // RNE
  return (unsigned short)u;
}
__device__ __forceinline__ float bf2f(unsigned short s){
  return __uint_as_float(((unsigned int)s) << 16);
}

__device__ __forceinline__ void gload_lds16(const unsigned short* g, unsigned short* l){
  __builtin_amdgcn_global_load_lds((const __attribute__((address_space(1))) void*)g,
                                   (__attribute__((address_space(3))) void*)l, 16, 0, 0);
}

// swizzled in-row offset: XOR the 8-element block index with (row&7)
#define SWZ(row, col) ((col) ^ (((row)&7)<<3))

// ------------------------------------------------------------------ fused casts
__global__ void cast3_kernel(const float* __restrict__ s0, unsigned short* __restrict__ d0, int n0,
                             const float* __restrict__ s1, unsigned short* __restrict__ d1, int n1,
                             const float* __restrict__ s2, unsigned short* __restrict__ d2, int n2){
  int total = n0 + n1 + n2;
  int stride = gridDim.x * blockDim.x;
  for (int i = blockIdx.x*blockDim.x + threadIdx.x; i < total; i += stride){
    const float* s; unsigned short* d; int j = i;
    if (j < n0){ s = s0; d = d0; }
    else if (j < n0 + n1){ j -= n0; s = s1; d = d1; }
    else { j -= n0 + n1; s = s2; d = d2; }
    float4 f = ((const float4*)s)[j];
    ushort4 u;
    u.x = f2bf(f.x); u.y = f2bf(f.y); u.z = f2bf(f.z); u.w = f2bf(f.w);
    ((ushort4*)d)[j] = u;
  }
}

// ------------------------------------------------------------------ GEMM (NT), 256x256 8-phase template
// BM=BN=256, BK=64, 8 waves (2M x 4N), 512 threads, 128 KiB LDS double-buffer.
// LDS tiles XOR-swizzled via pre-swizzled global SOURCE; reads apply the same XOR.
// Counted vmcnt(2) at phases 4/8. 2D-chunked XCD mapping (FETCH 123->47 MB, r6).
// BARRIER DIET (r11): end-of-MMA barriers dropped on phases 1/2/5/6. Safety:
// a stage into buffer X is only issued after a KEPT barrier that transitively
// orders it after all waves' WLG0-drains of X-reads:
//  - stage_4/8 (into the currently-read buf): after ENDBAR_3/7 (kept).
//  - stage_5/6/7 (into buf0): everyone past GBAR_4pre has drained phase-1/2/3
//    reads (WLG0_k precedes MMA_k precedes next-phase issue precedes GBAR_{k+1}).
//  - stage_1/2/3 (into buf1): buf1 reads drained before prev ENDBAR_7/8 (kept).
// Publish points (WVM2+ENDBAR at 4/8) unchanged -> counted-vmcnt pipeline intact.
// SPLITK: first/second half of the grid computes K/2 depth into C/C2 (fp32).
#define GBAR  do{ asm volatile("" ::: "memory"); __builtin_amdgcn_s_barrier(); asm volatile("" ::: "memory"); }while(0)
#define WVM2  asm volatile("s_waitcnt vmcnt(2)" ::: "memory")
#define WLG0  asm volatile("s_waitcnt lgkmcnt(0)" ::: "memory")
#define WLG8  asm volatile("s_waitcnt lgkmcnt(8)" ::: "memory")

#define LDA(sb_, mih_) do{ \
  _Pragma("unroll") \
  for (int m2 = 0; m2 < 4; ++m2) \
    _Pragma("unroll") \
    for (int ks = 0; ks < 2; ++ks) \
      aF[m2][ks] = frag(sb_, wmi*128 + (mih_)*64 + m2*16 + lm, ks); \
}while(0)

#define LDB(sb_, nih_) do{ \
  _Pragma("unroll") \
  for (int n2 = 0; n2 < 2; ++n2) \
    _Pragma("unroll") \
    for (int ks = 0; ks < 2; ++ks) \
      bF[(nih_)*2+n2][ks] = frag(sb_, wni*64 + (nih_)*32 + n2*16 + lm, ks); \
}while(0)

#define MMA(mih_, nih_) do{ \
  __builtin_amdgcn_s_setprio(1); \
  _Pragma("unroll") \
  for (int m2 = 0; m2 < 4; ++m2) \
    _Pragma("unroll") \
    for (int n2 = 0; n2 < 2; ++n2) \
      _Pragma("unroll") \
      for (int ks = 0; ks < 2; ++ks) \
        acc[(mih_)*4+m2][(nih_)*2+n2] = __builtin_amdgcn_mfma_f32_16x16x32_bf16( \
            aF[m2][ks], bF[(nih_)*2+n2][ks], acc[(mih_)*4+m2][(nih_)*2+n2], 0, 0, 0); \
  __builtin_amdgcn_s_setprio(0); \
}while(0)

template<bool OUT_BF16, bool SPLITK>
__global__ __launch_bounds__(512, 2) void gemm8p_kernel(
    const unsigned short* __restrict__ A, const unsigned short* __restrict__ B,
    void* __restrict__ C, void* __restrict__ C2, int N, int K, int lda, int tm){
  __shared__ __align__(16) unsigned short sA[2][256*64];
  __shared__ __align__(16) unsigned short sB[2][256*64];
  int tid = threadIdx.x;
  int wv = tid >> 6, ln = tid & 63, lm = ln & 15, quad = ln >> 4;
  // 2D-chunked bijective XCD mapping (requires tm%8==0; grid%8==0):
  //   xcd = wg&7 owns bm in [xcd*CM, (xcd+1)*CM), bn-major walk.
  int wg = blockIdx.x;
  int kh = 0;
  if (SPLITK){ int half = gridDim.x >> 1; if (wg >= half){ kh = 1; wg -= half; } }
  int xcd = wg & 7, l = wg >> 3;
  int CM = tm >> 3;
  int bn = l / CM, bm = xcd*CM + (l - bn*CM);
  int m0 = bm << 8, n0 = bn << 8;
  int wmi = wv >> 2, wni = wv & 3;
  const unsigned short* Ag = A + (size_t)m0*lda + (size_t)kh*K;
  const unsigned short* Bg = B + (size_t)n0*lda + (size_t)kh*K;

  f32x4 acc[8][4] = {};
  bf16x8 aF[4][2], bF[4][2];

  // iteration-invariant staging geometry: round r covers linear elem-blocks
  // e = r*512 + wv*64 + ln ; row = e>>3 ; cb = e&7 ; source col-block inverse-swizzled.
  int e0 = wv*64 + ln;
  int r0row = e0 >> 3, r0cb = e0 & 7;
  int e1 = 512 + e0;
  int r1row = e1 >> 3, r1cb = e1 & 7;
  size_t gsrc0 = (size_t)r0row*lda + ((r0cb ^ (r0row & 7)) << 3);
  size_t gsrc1 = (size_t)r1row*lda + ((r1cb ^ (r1row & 7)) << 3);
  int ldst0 = (wv*64) * 8;           // wave-uniform LDS elem offsets
  int ldst1 = (512 + wv*64) * 8;

  auto stage = [&](const unsigned short* g, unsigned short* sb, int h, int kt){
    gload_lds16(g + (size_t)h*128*lda + kt + gsrc0, sb + h*8192 + ldst0);
    gload_lds16(g + (size_t)h*128*lda + kt + gsrc1, sb + h*8192 + ldst1);
  };
  auto frag = [&](const unsigned short* sb, int row, int ks)->bf16x8 {
    return *(const bf16x8*)(sb + row*64 + ((((ks<<2)+quad) ^ (row & 7)) << 3));
  };

  // prologue: tile0 -> buf0 (4 half-tiles), tile1 A-h0 -> buf1; publish tile0.
  stage(Ag, sA[0], 0, 0);
  stage(Ag, sA[0], 1, 0);
  stage(Bg, sB[0], 0, 0);
  stage(Bg, sB[0], 1, 0);
  stage(Ag, sA[1], 0, 64);
  WVM2;
  GBAR;

  int nit = K >> 7;                   // 2 K-tiles (BK=64) per iteration
  for (int i = 0; i < nit; ++i){
    int k1 = (i<<7) + 64;             // odd tile of this iteration
    int k2 = ((i<<7) + 128) & (K-1);  // next even tile (wraps harmlessly at end)
    int k3 = ((i<<7) + 192) & (K-1);  // next odd tile

    // phase 1: Q(mi0-3 x ni0-1) on buf0  [end barrier dropped]
    LDA(sA[0], 0); LDB(sB[0], 0);
    stage(Ag, sA[1], 1, k1);
    WLG8;
    GBAR; WLG0; MMA(0,0);
    // phase 2: Q(mi0-3 x ni2-3)  [end barrier dropped]
    LDB(sB[0], 1);
    stage(Bg, sB[1], 0, k1);
    GBAR; WLG0; MMA(0,1);
    // phase 3: Q(mi4-7 x ni0-1)  [END BARRIER KEPT: phase 4 stages into buf0]
    LDA(sA[0], 1);
    stage(Bg, sB[1], 1, k1);
    GBAR; WLG0; MMA(1,0); GBAR;
    // phase 4: Q(mi4-7 x ni2-3); publish buf1
    stage(Ag, sA[0], 0, k2);
    GBAR; MMA(1,1); WVM2; GBAR;
    // phase 5: buf1  [end barrier dropped]
    LDA(sA[1], 0); LDB(sB[1], 0);
    stage(Ag, sA[0], 1, k2);
    WLG8;
    GBAR; WLG0; MMA(0,0);
    // phase 6  [end barrier dropped]
    LDB(sB[1], 1);
    stage(Bg, sB[0], 0, k2);
    GBAR; WLG0; MMA(0,1);
    // phase 7  [END BARRIER KEPT: phase 8 stages into buf1]
    LDA(sA[1], 1);
    stage(Bg, sB[0], 1, k2);
    GBAR; WLG0; MMA(1,0); GBAR;
    // phase 8: publish buf0 (next even tile)
    stage(Ag, sA[1], 0, k3);
    GBAR; MMA(1,1); WVM2; GBAR;
  }
  asm volatile("s_waitcnt vmcnt(0)" ::: "memory");  // drain trailing LDS-DMA before exit

  float* Cf = (float*)((SPLITK && kh) ? C2 : C);
  #pragma unroll
  for (int mi = 0; mi < 8; ++mi){
    int rowm = m0 + wmi*128 + mi*16 + quad*4;
    #pragma unroll
    for (int ni = 0; ni < 4; ++ni){
      int col = n0 + wni*64 + ni*16 + lm;
      size_t cb = (size_t)rowm * N + col;
      #pragma unroll
      for (int rr = 0; rr < 4; ++rr){
        float v = acc[mi][ni][rr];
        if (OUT_BF16) ((unsigned short*)C)[cb + (size_t)rr*N] = f2bf(v);
        else          Cf[cb + (size_t)rr*N] = v;
      }
    }
  }
}

#undef LDA
#undef LDB
#undef MMA
#undef GBAR
#undef WVM2
#undef WLG0
#undef WLG8

// ------------------------------------------------------------------ segmented cumsum over l
// NSEG=64 (SEGL=32): 4096 waves -> 16 waves/CU for the serial latency chains.
// kn is RECOMPUTED from qkvb_bf (bit-exact vs the old prep path: same bf16 inputs,
// same expf, same shuffle order) — kills the kb fp32 round-trip entirely.
#define NSEG 64
#define SEGL (SLEN/NSEG)   // 32
__global__ __launch_bounds__(64) void segsum_kernel(
    const unsigned short* __restrict__ qkvb, float* __restrict__ S){
  int bh = blockIdx.x, seg = blockIdx.y, ln = threadIdx.x;
  int b = bh >> 4, h = bh & 15;
  float s = 0.f;
  for (int i = 0; i < SEGL; ++i){
    int t = seg*SEGL + i;
    size_t rb = (size_t)(t*4+b) * NQPAD + (size_t)h*193;
    float kr = bf2f(qkvb[rb + 64 + ln]);
    float k1 = kr > 0.f ? kr + 1.f : __expf(kr);   // elu(x)+1
    float sk = k1;
    #pragma unroll
    for (int off = 1; off < 64; off <<= 1) sk += __shfl_xor(sk, off, 64);
    s += k1 / sk;
  }
  S[((size_t)bh*NSEG + seg)*64 + ln] = s;
}

// ------------------------------------------------------------------ fused prep + scan + denominators
// Recomputes qn/kn from qkvb_bf (bit-exact vs old prep), walks the inclusive
// cumsum, computes the three denominator reductions, and writes ALL downstream
// inputs: qb16/vb16 (bf16), kb16 (normalized bf16, swizzled), scal.
__global__ __launch_bounds__(64) void scan_kden_kernel(
    const unsigned short* __restrict__ qkvb, const float* __restrict__ S,
    unsigned short* __restrict__ qb16, unsigned short* __restrict__ vb16,
    unsigned short* __restrict__ kb16, float4* __restrict__ scal){
  int bh = blockIdx.x, seg = blockIdx.y, ln = threadIdx.x;
  int b = bh >> 4, h = bh & 15;
  float acc = 0.f;
  for (int s = 0; s < seg; ++s) acc += S[((size_t)bh*NSEG + s)*64 + ln];
  for (int i = 0; i < SEGL; ++i){
    int t = seg*SEGL + i;
    size_t rb = (size_t)(t*4+b) * NQPAD + (size_t)h*193;
    float qr = bf2f(qkvb[rb + ln]);
    float kr = bf2f(qkvb[rb + 64 + ln]);
    float vr = bf2f(qkvb[rb + 128 + ln]);
    float q1 = qr > 0.f ? qr + 1.f : __expf(qr);   // elu(x)+1
    float k1 = kr > 0.f ? kr + 1.f : __expf(kr);
    float sq = q1, sk = k1;
    #pragma unroll
    for (int off = 1; off < 64; off <<= 1){
      sq += __shfl_xor(sq, off, 64);
      sk += __shfl_xor(sk, off, 64);
    }
    float qn = q1 / sq, kn = k1 / sk;
    acc += kn;
    float a = acc;
    float d0 = (a - kn)*kn, d1 = a*qn, d2 = kn*qn;
    #pragma unroll
    for (int off = 1; off < 64; off <<= 1){
      d0 += __shfl_xor(d0, off, 64);
      d1 += __shfl_xor(d1, off, 64);
      d2 += __shfl_xor(d2, off, 64);
    }
    float kd  = (t == 0) ? 1.f : d0;
    float inv = 1.f / (kd + EPSV);
    float kf = kn * inv;
    size_t row = ((size_t)bh*SLEN + t)*64;
    qb16[row + SWZ(t, ln)] = f2bf(qn);
    vb16[row + ln] = f2bf(vr);
    kb16[row + SWZ(t, ln)] = f2bf(kf);
    if (ln == 0){
      float br = bf2f(qkvb[rb + 192]);
      float sb = 1.f / (1.f + __expf(-br));
      scal[(size_t)bh*SLEN + t] = make_float4(sb * kd, d2 * inv, SCALEV/(d1 + EPSV), 0.f);
    }
  }
}

// ------------------------------------------------------------------ precompute per (bh,chunk):
// Akk = K K^T (fp32, LDS), Bq = tril(Q K^T) incl diag (bf16 -> global, SWIZZLED),
// Dmat = (I + diag(b')*strictlow(Akk))^-1 diag(b')  (bf16 -> global, SWIZZLED).
// Kg/Qg are swizzled in global; fragment reads apply the same swizzle.
__global__ __launch_bounds__(64, 1) void precomp_kernel(
    const unsigned short* __restrict__ K16, const unsigned short* __restrict__ Q16,
    const float4* __restrict__ scal,
    unsigned short* __restrict__ Dg, unsigned short* __restrict__ Bg){
  __shared__ __align__(16) float sA[64*64];
  __shared__ float sbp[64];
  int inst = blockIdx.x;
  int bh = inst >> 5, ch = inst & 31;
  int ln = threadIdx.x, lm = ln & 15, quad = ln >> 4;
  const unsigned short* Kg = K16 + ((size_t)bh*SLEN + ch*CHK)*64;
  const unsigned short* Qg = Q16 + ((size_t)bh*SLEN + ch*CHK)*64;

  // Akk GEMM
  {
    f32x4 acc[4][4] = {};
    #pragma unroll
    for (int s = 0; s < 2; ++s){
      bf16x8 kf[4];
      #pragma unroll
      for (int i = 0; i < 4; ++i){
        int row = i*16+lm;
        kf[i] = *(const bf16x8*)(Kg + (size_t)row*64 + SWZ(row, s*32 + quad*8));
      }
      #pragma unroll
      for (int mi = 0; mi < 4; ++mi)
        #pragma unroll
        for (int ni = 0; ni < 4; ++ni)
          acc[mi][ni] = __builtin_amdgcn_mfma_f32_16x16x32_bf16(kf[mi], kf[ni], acc[mi][ni], 0, 0, 0);
    }
    #pragma unroll
    for (int mi = 0; mi < 4; ++mi)
      #pragma unroll
      for (int ni = 0; ni < 4; ++ni)
        #pragma unroll
        for (int rr = 0; rr < 4; ++rr)
          sA[(mi*16+quad*4+rr)*64 + ni*16+lm] = acc[mi][ni][rr];
  }
  sbp[ln] = scal[(size_t)bh*SLEN + ch*CHK + ln].x;
  __syncthreads();

  // Bq GEMM, masked swizzled store
  {
    f32x4 acc[4][4] = {};
    #pragma unroll
    for (int s = 0; s < 2; ++s){
      bf16x8 kf[4], qf[4];
      #pragma unroll
      for (int i = 0; i < 4; ++i){
        int row = i*16+lm;
        kf[i] = *(const bf16x8*)(Kg + (size_t)row*64 + SWZ(row, s*32 + quad*8));
        qf[i] = *(const bf16x8*)(Qg + (size_t)row*64 + SWZ(row, s*32 + quad*8));
      }
      #pragma unroll
      for (int mi = 0; mi < 4; ++mi)
        #pragma unroll
        for (int ni = 0; ni < 4; ++ni)
          acc[mi][ni] = __builtin_amdgcn_mfma_f32_16x16x32_bf16(qf[mi], kf[ni], acc[mi][ni], 0, 0, 0);
    }
    size_t io = (size_t)inst*4096;
    #pragma unroll
    for (int mi = 0; mi < 4; ++mi)
      #pragma unroll
      for (int ni = 0; ni < 4; ++ni)
        #pragma unroll
        for (int rr = 0; rr < 4; ++rr){
          int t = mi*16+quad*4+rr, j = ni*16+lm;
          float v = (j <= t) ? acc[mi][ni][rr] : 0.f;
          Bg[io + (size_t)t*64 + SWZ(t, j)] = f2bf(v);
        }
  }

  // triangular inversion: X = (I + diag(b')L)^-1 diag(b'); lane = column j
  {
    float x[64];
    x[0] = (ln == 0) ? sbp[0] : 0.f;
    #pragma unroll
    for (int i = 1; i < 64; ++i){
      float bi = sbp[i];
      float s = 0.f;
      #pragma unroll
      for (int m4 = 0; m4*4 < i; ++m4){
        float4 a = *(const float4*)&sA[i*64 + m4*4];
        if (m4*4+0 < i) s += a.x * x[m4*4+0];
        if (m4*4+1 < i) s += a.y * x[m4*4+1];
        if (m4*4+2 < i) s += a.z * x[m4*4+2];
        if (m4*4+3 < i) s += a.w * x[m4*4+3];
      }
      x[i] = ((ln == i) ? bi : 0.f) - bi*s;
    }
    size_t io = (size_t)inst*4096;
    #pragma unroll
    for (int i = 0; i < 64; ++i)
      Dg[io + (size_t)i*64 + SWZ(i, ln)] = f2bf(x[i]);
  }
}

// ------------------------------------------------------------------ chunked delta-rule, MFMA, r-split 4, 2 blocks/CU
// grid (64 bh, 4 rgroup); each block owns W rows r = rg*16..rg*16+15.
// LDS 74 KB (sB1 single-buffered, refilled after its post-phase2 barrier) ->
// 2 blocks/CU so the co-resident block hides barrier/vmcnt stalls.
__global__ __launch_bounds__(256, 2) void chunk_kernel(
    const unsigned short* __restrict__ K16, const unsigned short* __restrict__ Q16,
    const unsigned short* __restrict__ V16,
    const unsigned short* __restrict__ Dg, const unsigned short* __restrict__ Bg,
    const float4* __restrict__ scal, unsigned short* __restrict__ lo){
  __shared__ __align__(16) unsigned short sK[2][4096];   // K (t,d) swz
  __shared__ __align__(16) unsigned short sQ[2][4096];   // Q (t,d) swz
  __shared__ __align__(16) unsigned short sD[2][4096];   // D (t,j) swz
  __shared__ __align__(16) unsigned short sB1[4096];     // Bq (t,j) swz, single-buf
  __shared__ __align__(16) unsigned short sKT[4096];     // K^T (d,t) swz
  __shared__ __align__(16) unsigned short sV[2][1024];   // V strip (t, 16r) linear
  __shared__ __align__(16) unsigned short sX[1024];      // X^T (16r, t) swz
  __shared__ __align__(16) unsigned short sDT[1024];     // Delta^T (16r, t) swz
  __shared__ __align__(16) unsigned short sW[1024];      // W strip (16r, d) swz
  int bh = blockIdx.x, rg = blockIdx.y;
  int tid = threadIdx.x, wv = tid >> 6, ln = tid & 63, lm = ln & 15, quad = ln >> 4;
  size_t sb = (size_t)bh*SLEN*64;
  const unsigned short* Kg = K16 + sb;
  const unsigned short* Qg = Q16 + sb;
  const unsigned short* Vg = V16 + sb;
  const float4* scp = scal + (size_t)bh*SLEN;
  size_t lobase = (size_t)(bh>>4)*DMODEL + (size_t)(bh&15)*64 + rg*16;

  auto dma8 = [&](const unsigned short* g, unsigned short* s){
    #pragma unroll
    for (int it = 0; it < 2; ++it)
      gload_lds16(g + (wv*2+it)*512 + ln*8, s + (wv*2+it)*512);
  };
  auto dma_kqdv = [&](int ch, int p){
    size_t co = (size_t)ch*CHK*64;
    dma8(Kg + co, sK[p]);
    dma8(Qg + co, sQ[p]);
    dma8(Dg + ((size_t)bh*NCH + ch)*4096, sD[p]);
    if (wv == 0){
      gload_lds16(Vg + co + (size_t)(ln>>1)*64 + rg*16 + (ln&1)*8, sV[p]);
      gload_lds16(Vg + co + (size_t)(32 + (ln>>1))*64 + rg*16 + (ln&1)*8, sV[p] + 512);
    }
  };
  auto dma_b = [&](int ch){
    dma8(Bg + ((size_t)bh*NCH + ch)*4096, sB1);
  };
  auto frag = [&](const unsigned short* S, int row, int kb)->bf16x8 {
    return *(const bf16x8*)(S + row*64 + SWZ(row, kb));
  };

  if (tid < 128) ((uint4*)sW)[tid] = make_uint4(0u,0u,0u,0u);
  f32x4 Wacc = {0,0,0,0};
  dma_kqdv(0, 0);
  dma_b(0);

  for (int ch = 0; ch < NCH; ++ch){
    int p = ch & 1;
    const unsigned short* cK = sK[p];
    const unsigned short* cQ = sQ[p];
    const unsigned short* cD = sD[p];
    const unsigned short* cV = sV[p];
    int tb = ch*CHK + wv*16 + quad*4;
    float sz0 = scp[tb+0].z, sz1 = scp[tb+1].z, sz2 = scp[tb+2].z, sz3 = scp[tb+3].z;
    __builtin_amdgcn_s_waitcnt(0x0F70);   // vmcnt(0): this chunk's DMA (incl. late B)
    __syncthreads();                      // publish buf p + sB1 + sW spills
    if (ch + 1 < NCH) dma_kqdv(ch + 1, p ^ 1);   // overlap next K/Q/D/V DMA with phases 0-2

    // phase0: M = K W^T, Mq = Q W^T (wave = t-tile wv)
    f32x4 Macc = {0,0,0,0}, Mqacc = {0,0,0,0};
    #pragma unroll
    for (int s = 0; s < 2; ++s){
      int kb = s*32 + quad*8;
      bf16x8 ak = frag(cK, wv*16+lm, kb);
      bf16x8 aq = frag(cQ, wv*16+lm, kb);
      bf16x8 bw = frag(sW, lm, kb);
      Macc  = __builtin_amdgcn_mfma_f32_16x16x32_bf16(ak, bw, Macc, 0, 0, 0);
      Mqacc = __builtin_amdgcn_mfma_f32_16x16x32_bf16(aq, bw, Mqacc, 0, 0, 0);
    }
    // K-transpose read: thread -> row t = ln, cols d0..d0+15 (d0 = wv*16)
    int d0 = wv*16;
    uint4 kr0 = *(const uint4*)(cK + ln*64 + SWZ(ln, d0));
    uint4 kr1 = *(const uint4*)(cK + ln*64 + SWZ(ln, d0+8));
    // X = V - M; scatter X^T into sX
    #pragma unroll
    for (int rr = 0; rr < 4; ++rr){
      int t = wv*16 + quad*4 + rr;
      float x = bf2f(cV[t*16 + lm]) - Macc[rr];
      sX[lm*64 + SWZ(lm, t)] = f2bf(x);
    }
    // scatter K^T into sKT (per e: whole wave writes one row d)
    {
      const unsigned short* k0p = (const unsigned short*)&kr0;
      const unsigned short* k1p = (const unsigned short*)&kr1;
      #pragma unroll
      for (int e = 0; e < 8; ++e){
        int d = d0 + e;
        sKT[d*64 + SWZ(d, ln)] = k0p[e];
      }
      #pragma unroll
      for (int e = 0; e < 8; ++e){
        int d = d0 + 8 + e;
        sKT[d*64 + SWZ(d, ln)] = k1p[e];
      }
    }
    __syncthreads();   // sX, sKT ready

    // phase1: Delta[t,r] = D X  (A = D rows t, B = X^T rows r)
    f32x4 Dacc = {0,0,0,0};
    #pragma unroll
    for (int s = 0; s < 2; ++s){
      int kb = s*32 + quad*8;
      bf16x8 ad = frag(cD, wv*16+lm, kb);
      bf16x8 bx = frag(sX, lm, kb);
      Dacc = __builtin_amdgcn_mfma_f32_16x16x32_bf16(ad, bx, Dacc, 0, 0, 0);
    }
    #pragma unroll
    for (int rr = 0; rr < 4; ++rr){
      int t = wv*16 + quad*4 + rr;
      sDT[lm*64 + SWZ(lm, t)] = f2bf(Dacc[rr]);
    }
    __syncthreads();   // sDT ready

    // phase2: O = Mq + Bq Delta ; W += Delta^T K
    f32x4 Oacc = Mqacc;
    #pragma unroll
    for (int s = 0; s < 2; ++s){
      int kb = s*32 + quad*8;
      bf16x8 ab = frag(sB1, wv*16+lm, kb);
      bf16x8 bd = frag(sDT, lm, kb);
      Oacc = __builtin_amdgcn_mfma_f32_16x16x32_bf16(ab, bd, Oacc, 0, 0, 0);
      bf16x8 adt = frag(sDT, lm, kb);
      bf16x8 bkt = frag(sKT, wv*16+lm, kb);
      Wacc = __builtin_amdgcn_mfma_f32_16x16x32_bf16(adt, bkt, Wacc, 0, 0, 0);
    }
    #pragma unroll
    for (int rr = 0; rr < 4; ++rr){
      int tabs = ch*CHK + wv*16 + quad*4 + rr;
      float sz = (rr==0)?sz0:(rr==1)?sz1:(rr==2)?sz2:sz3;
      lo[lobase + (size_t)tabs*(BSZ*DMODEL) + lm] = f2bf(Oacc[rr] * sz);
    }
    __syncthreads();   // all sB1 (and phase2 LDS) reads of this chunk done
    if (ch + 1 < NCH) dma_b(ch + 1);   // refill single-buffered sB1
    // spill W strip (rows r = quad*4+rr, cols d = wv*16+lm); next loop-top
    // barrier orders these writes before phase0's sW reads.
    #pragma unroll
    for (int rr = 0; rr < 4; ++rr){
      int r = quad*4 + rr, d = wv*16 + lm;
      sW[r*64 + SWZ(r, d)] = f2bf(Wacc[rr]);
    }
  }
}

// ------------------------------------------------------------------ residual + layernorm (sums split-K partials)
__global__ __launch_bounds__(256) void ln_kernel(
    const float* __restrict__ hin, const float* __restrict__ a0,
    const float* __restrict__ a1,
    const float* __restrict__ g, const float* __restrict__ bta,
    float* __restrict__ out){
  int row = blockIdx.x, tid = threadIdx.x;
  size_t rb = (size_t)row * DMODEL;
  float4 hv = ((const float4*)(hin + rb))[tid];
  float4 v0 = ((const float4*)(a0 + rb))[tid];
  float4 v1 = ((const float4*)(a1 + rb))[tid];
  float4 x;
  x.x = hv.x + v0.x + v1.x; x.y = hv.y + v0.y + v1.y;
  x.z = hv.z + v0.z + v1.z; x.w = hv.w + v0.w + v1.w;
  float s  = x.x + x.y + x.z + x.w;
  float ss = x.x*x.x + x.y*x.y + x.z*x.z + x.w*x.w;
  #pragma unroll
  for (int off = 1; off < 64; off <<= 1){
    s  += __shfl_xor(s , off, 64);
    ss += __shfl_xor(ss, off, 64);
  }
  __shared__ float ls[4], lq[4];
  int wv = tid >> 6, ln = tid & 63;
  if (ln == 0){ ls[wv] = s; lq[wv] = ss; }
  __syncthreads();
  s  = ls[0] + ls[1] + ls[2] + ls[3];
  ss = lq[0] + lq[1] + lq[2] + lq[3];
  float mu  = s * (1.f/DMODEL);
  float var = ss * (1.f/DMODEL) - mu*mu;
  float rstd = rsqrtf(var + EPSV);
  float4 gv = ((const float4*)g)[tid], bv = ((const float4*)bta)[tid];
  float4 o;
  o.x = (x.x-mu)*rstd*gv.x + bv.x;
  o.y = (x.y-mu)*rstd*gv.y + bv.y;
  o.z = (x.z-mu)*rstd*gv.z + bv.z;
  o.w = (x.w-mu)*rstd*gv.w + bv.w;
  ((float4*)(out + rb))[tid] = o;
}

// ------------------------------------------------------------------ launch
// Workspace budget ~218 MB (ws overflow at ~251 MB killed rounds 3/4/7).
extern "C" void kernel_launch(void* const* d_in, const int* in_sizes, int n_in,
                              void* d_out, int out_size, void* d_ws, size_t ws_size,
                              hipStream_t stream){
  const float* h     = (const float*)d_in[0];
  const float* wqkvb = (const float*)d_in[1];
  const float* wo    = (const float*)d_in[2];
  const float* lng   = (const float*)d_in[3];
  const float* lnb   = (const float*)d_in[4];
  float* out = (float*)d_out;

  char* w = (char*)d_ws;
  auto take = [&](size_t bytes)->char*{
    char* p = w; w += (bytes + 255) & ~(size_t)255; return p;
  };
  unsigned short* h_bf    = (unsigned short*)take((size_t)MROWS*DMODEL*2);
  unsigned short* wq_bf   = (unsigned short*)take((size_t)NQPAD*DMODEL*2);
  unsigned short* wo_bf   = (unsigned short*)take((size_t)DMODEL*DMODEL*2);
  unsigned short* qkvb_bf = (unsigned short*)take((size_t)MROWS*NQPAD*2);
  float* attn1 = (float*)take((size_t)MROWS*DMODEL*4 + 4096);   // splitK partial 1
  float* Ab    = (float*)take((size_t)MROWS*DMODEL*4);   // aliased: D+Bq after scan_kden; attn0 after chunk
  float4* scal = (float4*)take((size_t)64*SLEN*16 + 4096);
  unsigned short* lo_bf = (unsigned short*)take((size_t)MROWS*DMODEL*2);
  float* Sseg = (float*)take((size_t)64*NSEG*64*4);
  unsigned short* kb16 = (unsigned short*)take((size_t)MROWS*DMODEL*2);
  unsigned short* qb16 = (unsigned short*)take((size_t)MROWS*DMODEL*2);
  unsigned short* vb16 = (unsigned short*)take((size_t)MROWS*DMODEL*2);
  unsigned short* Dg = (unsigned short*)Ab;
  unsigned short* Bg = (unsigned short*)Ab + (size_t)64*NCH*4096;
  float* attn0 = Ab;

  cast3_kernel<<<2048, 256, 0, stream>>>(h, h_bf, MROWS*DMODEL/4,
                                         wqkvb, wq_bf, NQKVB*DMODEL/4,
                                         wo, wo_bf, DMODEL*DMODEL/4);

  gemm8p_kernel<true, false><<<(MROWS/256)*(NQPAD/256), 512, 0, stream>>>(
      h_bf, wq_bf, qkvb_bf, nullptr, NQPAD, DMODEL, DMODEL, MROWS/256);

  segsum_kernel<<<dim3(64, NSEG), 64, 0, stream>>>(qkvb_bf, Sseg);
  scan_kden_kernel<<<dim3(64, NSEG), 64, 0, stream>>>(qkvb_bf, Sseg, qb16, vb16, kb16, scal);
  precomp_kernel<<<64*NCH, 64, 0, stream>>>(kb16, qb16, scal, Dg, Bg);
  chunk_kernel<<<dim3(64, 4), 256, 0, stream>>>(kb16, qb16, vb16, Dg, Bg, scal, lo_bf);

  // split-K=2: 256 blocks (full machine), halves write fp32 partials summed in ln
  gemm8p_kernel<false, true><<<2*(MROWS/256)*(DMODEL/256), 512, 0, stream>>>(
      lo_bf, wo_bf, attn0, attn1, DMODEL, DMODEL/2, DMODEL, MROWS/256);

  ln_kernel<<<MROWS, 256, 0, stream>>>(h, attn0, attn1, lng, lnb, out);
  (void)in_sizes; (void)n_in; (void)out_size; (void)ws_size;
}

// Round 12
// 357.320 us; speedup vs baseline: 1.0504x; 1.0144x over previous
//
#include <hip/hip_runtime.h>
#include <cstdint>
#include <cstddef>

#define D_HEAD   64
#define NHEAD    16
#define DMODEL   1024
#define SLEN     2048
#define BSZ      4
#define MROWS    (SLEN*BSZ)            // 8192
#define NQKVB    (NHEAD*(3*D_HEAD+1))  // 3088
#define NQPAD    3328                  // padded to 13*256 for the 256-tile GEMM
#define EPSV     1e-5f
#define SCALEV   0.125f                // 1/sqrt(64)
#define CHK      64                    // chunk length
#define NCH      (SLEN/CHK)            // 32

typedef short bf16x8 __attribute__((ext_vector_type(8)));
typedef float f32x4  __attribute__((ext_vector_type(4)));

__device__ __forceinline__ unsigned short f2bf(float f){
  unsigned int u = __float_as_uint(f);
  u = (u + 0x7fffu + ((u >> 16) & 1u)) >> 16;   // RNE
  return (unsigned short)u;
}
__device__ __forceinline__ float bf2f(unsigned short s){
  return __uint_as_float(((unsigned int)s) << 16);
}

__device__ __forceinline__ void gload_lds16(const unsigned short* g, unsigned short* l){
  __builtin_amdgcn_global_load_lds((const __attribute__((address_space(1))) void*)g,
                                   (__attribute__((address_space(3))) void*)l, 16, 0, 0);
}

// swizzled in-row offset: XOR the 8-element block index with (row&7)
#define SWZ(row, col) ((col) ^ (((row)&7)<<3))

// ------------------------------------------------------------------ fused casts
__global__ void cast3_kernel(const float* __restrict__ s0, unsigned short* __restrict__ d0, int n0,
                             const float* __restrict__ s1, unsigned short* __restrict__ d1, int n1,
                             const float* __restrict__ s2, unsigned short* __restrict__ d2, int n2){
  int total = n0 + n1 + n2;
  int stride = gridDim.x * blockDim.x;
  for (int i = blockIdx.x*blockDim.x + threadIdx.x; i < total; i += stride){
    const float* s; unsigned short* d; int j = i;
    if (j < n0){ s = s0; d = d0; }
    else if (j < n0 + n1){ j -= n0; s = s1; d = d1; }
    else { j -= n0 + n1; s = s2; d = d2; }
    float4 f = ((const float4*)s)[j];
    ushort4 u;
    u.x = f2bf(f.x); u.y = f2bf(f.y); u.z = f2bf(f.z); u.w = f2bf(f.w);
    ((ushort4*)d)[j] = u;
  }
}

// ------------------------------------------------------------------ GEMM (NT), 256x256 8-phase template
// BM=BN=256, BK=64, 8 waves (2M x 4N), 512 threads, 128 KiB LDS double-buffer.
// LDS tiles XOR-swizzled via pre-swizzled global SOURCE; reads apply the same XOR.
// Counted vmcnt(2) publishes at phases 4/8. 2D-chunked XCD mapping (r6).
// BARRIER DIET r11 (16->12, +6%) + r12 (12->6). Kept barriers and their jobs:
//  - pre_1/pre_5 (post-WLG8): alignment cadence only.
//  - end_3/end_7: guard phases 4/8's stage into the currently-read buffer
//    (all waves' WLG0-drains of that buffer's ds_reads precede these barriers).
//  - pub_4/pub_8 (WVM2+GBAR): publish a fully-staged buffer; counted-vmcnt
//    pipeline unchanged (never drains to 0 mid-loop).
// Dropped barriers ordered nothing: each phase reads a buffer published at the
// last pub_*, and stages into a buffer whose reads drained before the last
// kept end_* (WLG0_k < MMA_k < end-barrier in every wave's program order).
// SPLITK: first/second half of the grid computes K/2 depth into C/C2 (fp32).
#define GBAR  do{ asm volatile("" ::: "memory"); __builtin_amdgcn_s_barrier(); asm volatile("" ::: "memory"); }while(0)
#define WVM2  asm volatile("s_waitcnt vmcnt(2)" ::: "memory")
#define WLG0  asm volatile("s_waitcnt lgkmcnt(0)" ::: "memory")
#define WLG8  asm volatile("s_waitcnt lgkmcnt(8)" ::: "memory")

#define LDA(sb_, mih_) do{ \
  _Pragma("unroll") \
  for (int m2 = 0; m2 < 4; ++m2) \
    _Pragma("unroll") \
    for (int ks = 0; ks < 2; ++ks) \
      aF[m2][ks] = frag(sb_, wmi*128 + (mih_)*64 + m2*16 + lm, ks); \
}while(0)

#define LDB(sb_, nih_) do{ \
  _Pragma("unroll") \
  for (int n2 = 0; n2 < 2; ++n2) \
    _Pragma("unroll") \
    for (int ks = 0; ks < 2; ++ks) \
      bF[(nih_)*2+n2][ks] = frag(sb_, wni*64 + (nih_)*32 + n2*16 + lm, ks); \
}while(0)

#define MMA(mih_, nih_) do{ \
  __builtin_amdgcn_s_setprio(1); \
  _Pragma("unroll") \
  for (int m2 = 0; m2 < 4; ++m2) \
    _Pragma("unroll") \
    for (int n2 = 0; n2 < 2; ++n2) \
      _Pragma("unroll") \
      for (int ks = 0; ks < 2; ++ks) \
        acc[(mih_)*4+m2][(nih_)*2+n2] = __builtin_amdgcn_mfma_f32_16x16x32_bf16( \
            aF[m2][ks], bF[(nih_)*2+n2][ks], acc[(mih_)*4+m2][(nih_)*2+n2], 0, 0, 0); \
  __builtin_amdgcn_s_setprio(0); \
}while(0)

template<bool OUT_BF16, bool SPLITK>
__global__ __launch_bounds__(512, 2) void gemm8p_kernel(
    const unsigned short* __restrict__ A, const unsigned short* __restrict__ B,
    void* __restrict__ C, void* __restrict__ C2, int N, int K, int lda, int tm){
  __shared__ __align__(16) unsigned short sA[2][256*64];
  __shared__ __align__(16) unsigned short sB[2][256*64];
  int tid = threadIdx.x;
  int wv = tid >> 6, ln = tid & 63, lm = ln & 15, quad = ln >> 4;
  // 2D-chunked bijective XCD mapping (requires tm%8==0; grid%8==0):
  //   xcd = wg&7 owns bm in [xcd*CM, (xcd+1)*CM), bn-major walk.
  int wg = blockIdx.x;
  int kh = 0;
  if (SPLITK){ int half = gridDim.x >> 1; if (wg >= half){ kh = 1; wg -= half; } }
  int xcd = wg & 7, l = wg >> 3;
  int CM = tm >> 3;
  int bn = l / CM, bm = xcd*CM + (l - bn*CM);
  int m0 = bm << 8, n0 = bn << 8;
  int wmi = wv >> 2, wni = wv & 3;
  const unsigned short* Ag = A + (size_t)m0*lda + (size_t)kh*K;
  const unsigned short* Bg = B + (size_t)n0*lda + (size_t)kh*K;

  f32x4 acc[8][4] = {};
  bf16x8 aF[4][2], bF[4][2];

  // iteration-invariant staging geometry: round r covers linear elem-blocks
  // e = r*512 + wv*64 + ln ; row = e>>3 ; cb = e&7 ; source col-block inverse-swizzled.
  int e0 = wv*64 + ln;
  int r0row = e0 >> 3, r0cb = e0 & 7;
  int e1 = 512 + e0;
  int r1row = e1 >> 3, r1cb = e1 & 7;
  size_t gsrc0 = (size_t)r0row*lda + ((r0cb ^ (r0row & 7)) << 3);
  size_t gsrc1 = (size_t)r1row*lda + ((r1cb ^ (r1row & 7)) << 3);
  int ldst0 = (wv*64) * 8;           // wave-uniform LDS elem offsets
  int ldst1 = (512 + wv*64) * 8;

  auto stage = [&](const unsigned short* g, unsigned short* sb, int h, int kt){
    gload_lds16(g + (size_t)h*128*lda + kt + gsrc0, sb + h*8192 + ldst0);
    gload_lds16(g + (size_t)h*128*lda + kt + gsrc1, sb + h*8192 + ldst1);
  };
  auto frag = [&](const unsigned short* sb, int row, int ks)->bf16x8 {
    return *(const bf16x8*)(sb + row*64 + ((((ks<<2)+quad) ^ (row & 7)) << 3));
  };

  // prologue: tile0 -> buf0 (4 half-tiles), tile1 A-h0 -> buf1; publish tile0.
  stage(Ag, sA[0], 0, 0);
  stage(Ag, sA[0], 1, 0);
  stage(Bg, sB[0], 0, 0);
  stage(Bg, sB[0], 1, 0);
  stage(Ag, sA[1], 0, 64);
  WVM2;
  GBAR;

  int nit = K >> 7;                   // 2 K-tiles (BK=64) per iteration
  for (int i = 0; i < nit; ++i){
    int k1 = (i<<7) + 64;             // odd tile of this iteration
    int k2 = ((i<<7) + 128) & (K-1);  // next even tile (wraps harmlessly at end)
    int k3 = ((i<<7) + 192) & (K-1);  // next odd tile

    // phase 1: Q(mi0-3 x ni0-1) on buf0  [pre-barrier kept: alignment]
    LDA(sA[0], 0); LDB(sB[0], 0);
    stage(Ag, sA[1], 1, k1);
    WLG8;
    GBAR; WLG0; MMA(0,0);
    // phase 2: Q(mi0-3 x ni2-3)  [no barriers]
    LDB(sB[0], 1);
    stage(Bg, sB[1], 0, k1);
    WLG0; MMA(0,1);
    // phase 3: Q(mi4-7 x ni0-1)  [END BARRIER KEPT: phase 4 stages into buf0]
    LDA(sA[0], 1);
    stage(Bg, sB[1], 1, k1);
    WLG0; MMA(1,0); GBAR;
    // phase 4: Q(mi4-7 x ni2-3); publish buf1 (WVM2 after reg-only MMA)
    stage(Ag, sA[0], 0, k2);
    MMA(1,1); WVM2; GBAR;
    // phase 5: buf1  [pre-barrier kept: alignment]
    LDA(sA[1], 0); LDB(sB[1], 0);
    stage(Ag, sA[0], 1, k2);
    WLG8;
    GBAR; WLG0; MMA(0,0);
    // phase 6  [no barriers]
    LDB(sB[1], 1);
    stage(Bg, sB[0], 0, k2);
    WLG0; MMA(0,1);
    // phase 7  [END BARRIER KEPT: phase 8 stages into buf1]
    LDA(sA[1], 1);
    stage(Bg, sB[0], 1, k2);
    WLG0; MMA(1,0); GBAR;
    // phase 8: publish buf0 (next even tile)
    stage(Ag, sA[1], 0, k3);
    MMA(1,1); WVM2; GBAR;
  }
  asm volatile("s_waitcnt vmcnt(0)" ::: "memory");  // drain trailing LDS-DMA before exit

  float* Cf = (float*)((SPLITK && kh) ? C2 : C);
  #pragma unroll
  for (int mi = 0; mi < 8; ++mi){
    int rowm = m0 + wmi*128 + mi*16 + quad*4;
    #pragma unroll
    for (int ni = 0; ni < 4; ++ni){
      int col = n0 + wni*64 + ni*16 + lm;
      size_t cb = (size_t)rowm * N + col;
      #pragma unroll
      for (int rr = 0; rr < 4; ++rr){
        float v = acc[mi][ni][rr];
        if (OUT_BF16) ((unsigned short*)C)[cb + (size_t)rr*N] = f2bf(v);
        else          Cf[cb + (size_t)rr*N] = v;
      }
    }
  }
}

#undef LDA
#undef LDB
#undef MMA
#undef GBAR
#undef WVM2
#undef WLG0
#undef WLG8

// ------------------------------------------------------------------ segmented cumsum over l
// NSEG=64 (SEGL=32): 4096 waves -> 16 waves/CU for the serial latency chains.
// kn is RECOMPUTED from qkvb_bf (bit-exact vs the old prep path: same bf16 inputs,
// same expf, same shuffle order) — kills the kb fp32 round-trip entirely.
#define NSEG 64
#define SEGL (SLEN/NSEG)   // 32
__global__ __launch_bounds__(64) void segsum_kernel(
    const unsigned short* __restrict__ qkvb, float* __restrict__ S){
  int bh = blockIdx.x, seg = blockIdx.y, ln = threadIdx.x;
  int b = bh >> 4, h = bh & 15;
  float s = 0.f;
  for (int i = 0; i < SEGL; ++i){
    int t = seg*SEGL + i;
    size_t rb = (size_t)(t*4+b) * NQPAD + (size_t)h*193;
    float kr = bf2f(qkvb[rb + 64 + ln]);
    float k1 = kr > 0.f ? kr + 1.f : __expf(kr);   // elu(x)+1
    float sk = k1;
    #pragma unroll
    for (int off = 1; off < 64; off <<= 1) sk += __shfl_xor(sk, off, 64);
    s += k1 / sk;
  }
  S[((size_t)bh*NSEG + seg)*64 + ln] = s;
}

// ------------------------------------------------------------------ fused prep + scan + denominators
// Recomputes qn/kn from qkvb_bf (bit-exact vs old prep), walks the inclusive
// cumsum, computes the three denominator reductions, and writes ALL downstream
// inputs: qb16/vb16 (bf16), kb16 (normalized bf16, swizzled), scal.
__global__ __launch_bounds__(64) void scan_kden_kernel(
    const unsigned short* __restrict__ qkvb, const float* __restrict__ S,
    unsigned short* __restrict__ qb16, unsigned short* __restrict__ vb16,
    unsigned short* __restrict__ kb16, float4* __restrict__ scal){
  int bh = blockIdx.x, seg = blockIdx.y, ln = threadIdx.x;
  int b = bh >> 4, h = bh & 15;
  float acc = 0.f;
  for (int s = 0; s < seg; ++s) acc += S[((size_t)bh*NSEG + s)*64 + ln];
  for (int i = 0; i < SEGL; ++i){
    int t = seg*SEGL + i;
    size_t rb = (size_t)(t*4+b) * NQPAD + (size_t)h*193;
    float qr = bf2f(qkvb[rb + ln]);
    float kr = bf2f(qkvb[rb + 64 + ln]);
    float vr = bf2f(qkvb[rb + 128 + ln]);
    float q1 = qr > 0.f ? qr + 1.f : __expf(qr);   // elu(x)+1
    float k1 = kr > 0.f ? kr + 1.f : __expf(kr);
    float sq = q1, sk = k1;
    #pragma unroll
    for (int off = 1; off < 64; off <<= 1){
      sq += __shfl_xor(sq, off, 64);
      sk += __shfl_xor(sk, off, 64);
    }
    float qn = q1 / sq, kn = k1 / sk;
    acc += kn;
    float a = acc;
    float d0 = (a - kn)*kn, d1 = a*qn, d2 = kn*qn;
    #pragma unroll
    for (int off = 1; off < 64; off <<= 1){
      d0 += __shfl_xor(d0, off, 64);
      d1 += __shfl_xor(d1, off, 64);
      d2 += __shfl_xor(d2, off, 64);
    }
    float kd  = (t == 0) ? 1.f : d0;
    float inv = 1.f / (kd + EPSV);
    float kf = kn * inv;
    size_t row = ((size_t)bh*SLEN + t)*64;
    qb16[row + SWZ(t, ln)] = f2bf(qn);
    vb16[row + ln] = f2bf(vr);
    kb16[row + SWZ(t, ln)] = f2bf(kf);
    if (ln == 0){
      float br = bf2f(qkvb[rb + 192]);
      float sb = 1.f / (1.f + __expf(-br));
      scal[(size_t)bh*SLEN + t] = make_float4(sb * kd, d2 * inv, SCALEV/(d1 + EPSV), 0.f);
    }
  }
}

// ------------------------------------------------------------------ precompute per (bh,chunk):
// Akk = K K^T (fp32, LDS), Bq = tril(Q K^T) incl diag (bf16 -> global, SWIZZLED),
// Dmat = (I + diag(b')*strictlow(Akk))^-1 diag(b')  (bf16 -> global, SWIZZLED).
// Kg/Qg are swizzled in global; fragment reads apply the same swizzle.
__global__ __launch_bounds__(64, 1) void precomp_kernel(
    const unsigned short* __restrict__ K16, const unsigned short* __restrict__ Q16,
    const float4* __restrict__ scal,
    unsigned short* __restrict__ Dg, unsigned short* __restrict__ Bg){
  __shared__ __align__(16) float sA[64*64];
  __shared__ float sbp[64];
  int inst = blockIdx.x;
  int bh = inst >> 5, ch = inst & 31;
  int ln = threadIdx.x, lm = ln & 15, quad = ln >> 4;
  const unsigned short* Kg = K16 + ((size_t)bh*SLEN + ch*CHK)*64;
  const unsigned short* Qg = Q16 + ((size_t)bh*SLEN + ch*CHK)*64;

  // Akk GEMM
  {
    f32x4 acc[4][4] = {};
    #pragma unroll
    for (int s = 0; s < 2; ++s){
      bf16x8 kf[4];
      #pragma unroll
      for (int i = 0; i < 4; ++i){
        int row = i*16+lm;
        kf[i] = *(const bf16x8*)(Kg + (size_t)row*64 + SWZ(row, s*32 + quad*8));
      }
      #pragma unroll
      for (int mi = 0; mi < 4; ++mi)
        #pragma unroll
        for (int ni = 0; ni < 4; ++ni)
          acc[mi][ni] = __builtin_amdgcn_mfma_f32_16x16x32_bf16(kf[mi], kf[ni], acc[mi][ni], 0, 0, 0);
    }
    #pragma unroll
    for (int mi = 0; mi < 4; ++mi)
      #pragma unroll
      for (int ni = 0; ni < 4; ++ni)
        #pragma unroll
        for (int rr = 0; rr < 4; ++rr)
          sA[(mi*16+quad*4+rr)*64 + ni*16+lm] = acc[mi][ni][rr];
  }
  sbp[ln] = scal[(size_t)bh*SLEN + ch*CHK + ln].x;
  __syncthreads();

  // Bq GEMM, masked swizzled store
  {
    f32x4 acc[4][4] = {};
    #pragma unroll
    for (int s = 0; s < 2; ++s){
      bf16x8 kf[4], qf[4];
      #pragma unroll
      for (int i = 0; i < 4; ++i){
        int row = i*16+lm;
        kf[i] = *(const bf16x8*)(Kg + (size_t)row*64 + SWZ(row, s*32 + quad*8));
        qf[i] = *(const bf16x8*)(Qg + (size_t)row*64 + SWZ(row, s*32 + quad*8));
      }
      #pragma unroll
      for (int mi = 0; mi < 4; ++mi)
        #pragma unroll
        for (int ni = 0; ni < 4; ++ni)
          acc[mi][ni] = __builtin_amdgcn_mfma_f32_16x16x32_bf16(qf[mi], kf[ni], acc[mi][ni], 0, 0, 0);
    }
    size_t io = (size_t)inst*4096;
    #pragma unroll
    for (int mi = 0; mi < 4; ++mi)
      #pragma unroll
      for (int ni = 0; ni < 4; ++ni)
        #pragma unroll
        for (int rr = 0; rr < 4; ++rr){
          int t = mi*16+quad*4+rr, j = ni*16+lm;
          float v = (j <= t) ? acc[mi][ni][rr] : 0.f;
          Bg[io + (size_t)t*64 + SWZ(t, j)] = f2bf(v);
        }
  }

  // triangular inversion: X = (I + diag(b')L)^-1 diag(b'); lane = column j
  {
    float x[64];
    x[0] = (ln == 0) ? sbp[0] : 0.f;
    #pragma unroll
    for (int i = 1; i < 64; ++i){
      float bi = sbp[i];
      float s = 0.f;
      #pragma unroll
      for (int m4 = 0; m4*4 < i; ++m4){
        float4 a = *(const float4*)&sA[i*64 + m4*4];
        if (m4*4+0 < i) s += a.x * x[m4*4+0];
        if (m4*4+1 < i) s += a.y * x[m4*4+1];
        if (m4*4+2 < i) s += a.z * x[m4*4+2];
        if (m4*4+3 < i) s += a.w * x[m4*4+3];
      }
      x[i] = ((ln == i) ? bi : 0.f) - bi*s;
    }
    size_t io = (size_t)inst*4096;
    #pragma unroll
    for (int i = 0; i < 64; ++i)
      Dg[io + (size_t)i*64 + SWZ(i, ln)] = f2bf(x[i]);
  }
}

// ------------------------------------------------------------------ chunked delta-rule, MFMA, r-split 4, 2 blocks/CU
// grid (64 bh, 4 rgroup); each block owns W rows r = rg*16..rg*16+15.
// LDS 74 KB (sB1 single-buffered, refilled after its post-phase2 barrier) ->
// 2 blocks/CU so the co-resident block hides barrier/vmcnt stalls.
__global__ __launch_bounds__(256, 2) void chunk_kernel(
    const unsigned short* __restrict__ K16, const unsigned short* __restrict__ Q16,
    const unsigned short* __restrict__ V16,
    const unsigned short* __restrict__ Dg, const unsigned short* __restrict__ Bg,
    const float4* __restrict__ scal, unsigned short* __restrict__ lo){
  __shared__ __align__(16) unsigned short sK[2][4096];   // K (t,d) swz
  __shared__ __align__(16) unsigned short sQ[2][4096];   // Q (t,d) swz
  __shared__ __align__(16) unsigned short sD[2][4096];   // D (t,j) swz
  __shared__ __align__(16) unsigned short sB1[4096];     // Bq (t,j) swz, single-buf
  __shared__ __align__(16) unsigned short sKT[4096];     // K^T (d,t) swz
  __shared__ __align__(16) unsigned short sV[2][1024];   // V strip (t, 16r) linear
  __shared__ __align__(16) unsigned short sX[1024];      // X^T (16r, t) swz
  __shared__ __align__(16) unsigned short sDT[1024];     // Delta^T (16r, t) swz
  __shared__ __align__(16) unsigned short sW[1024];      // W strip (16r, d) swz
  int bh = blockIdx.x, rg = blockIdx.y;
  int tid = threadIdx.x, wv = tid >> 6, ln = tid & 63, lm = ln & 15, quad = ln >> 4;
  size_t sb = (size_t)bh*SLEN*64;
  const unsigned short* Kg = K16 + sb;
  const unsigned short* Qg = Q16 + sb;
  const unsigned short* Vg = V16 + sb;
  const float4* scp = scal + (size_t)bh*SLEN;
  size_t lobase = (size_t)(bh>>4)*DMODEL + (size_t)(bh&15)*64 + rg*16;

  auto dma8 = [&](const unsigned short* g, unsigned short* s){
    #pragma unroll
    for (int it = 0; it < 2; ++it)
      gload_lds16(g + (wv*2+it)*512 + ln*8, s + (wv*2+it)*512);
  };
  auto dma_kqdv = [&](int ch, int p){
    size_t co = (size_t)ch*CHK*64;
    dma8(Kg + co, sK[p]);
    dma8(Qg + co, sQ[p]);
    dma8(Dg + ((size_t)bh*NCH + ch)*4096, sD[p]);
    if (wv == 0){
      gload_lds16(Vg + co + (size_t)(ln>>1)*64 + rg*16 + (ln&1)*8, sV[p]);
      gload_lds16(Vg + co + (size_t)(32 + (ln>>1))*64 + rg*16 + (ln&1)*8, sV[p] + 512);
    }
  };
  auto dma_b = [&](int ch){
    dma8(Bg + ((size_t)bh*NCH + ch)*4096, sB1);
  };
  auto frag = [&](const unsigned short* S, int row, int kb)->bf16x8 {
    return *(const bf16x8*)(S + row*64 + SWZ(row, kb));
  };

  if (tid < 128) ((uint4*)sW)[tid] = make_uint4(0u,0u,0u,0u);
  f32x4 Wacc = {0,0,0,0};
  dma_kqdv(0, 0);
  dma_b(0);

  for (int ch = 0; ch < NCH; ++ch){
    int p = ch & 1;
    const unsigned short* cK = sK[p];
    const unsigned short* cQ = sQ[p];
    const unsigned short* cD = sD[p];
    const unsigned short* cV = sV[p];
    int tb = ch*CHK + wv*16 + quad*4;
    float sz0 = scp[tb+0].z, sz1 = scp[tb+1].z, sz2 = scp[tb+2].z, sz3 = scp[tb+3].z;
    __builtin_amdgcn_s_waitcnt(0x0F70);   // vmcnt(0): this chunk's DMA (incl. late B)
    __syncthreads();                      // publish buf p + sB1 + sW spills
    if (ch + 1 < NCH) dma_kqdv(ch + 1, p ^ 1);   // overlap next K/Q/D/V DMA with phases 0-2

    // phase0: M = K W^T, Mq = Q W^T (wave = t-tile wv)
    f32x4 Macc = {0,0,0,0}, Mqacc = {0,0,0,0};
    #pragma unroll
    for (int s = 0; s < 2; ++s){
      int kb = s*32 + quad*8;
      bf16x8 ak = frag(cK, wv*16+lm, kb);
      bf16x8 aq = frag(cQ, wv*16+lm, kb);
      bf16x8 bw = frag(sW, lm, kb);
      Macc  = __builtin_amdgcn_mfma_f32_16x16x32_bf16(ak, bw, Macc, 0, 0, 0);
      Mqacc = __builtin_amdgcn_mfma_f32_16x16x32_bf16(aq, bw, Mqacc, 0, 0, 0);
    }
    // K-transpose read: thread -> row t = ln, cols d0..d0+15 (d0 = wv*16)
    int d0 = wv*16;
    uint4 kr0 = *(const uint4*)(cK + ln*64 + SWZ(ln, d0));
    uint4 kr1 = *(const uint4*)(cK + ln*64 + SWZ(ln, d0+8));
    // X = V - M; scatter X^T into sX
    #pragma unroll
    for (int rr = 0; rr < 4; ++rr){
      int t = wv*16 + quad*4 + rr;
      float x = bf2f(cV[t*16 + lm]) - Macc[rr];
      sX[lm*64 + SWZ(lm, t)] = f2bf(x);
    }
    // scatter K^T into sKT (per e: whole wave writes one row d)
    {
      const unsigned short* k0p = (const unsigned short*)&kr0;
      const unsigned short* k1p = (const unsigned short*)&kr1;
      #pragma unroll
      for (int e = 0; e < 8; ++e){
        int d = d0 + e;
        sKT[d*64 + SWZ(d, ln)] = k0p[e];
      }
      #pragma unroll
      for (int e = 0; e < 8; ++e){
        int d = d0 + 8 + e;
        sKT[d*64 + SWZ(d, ln)] = k1p[e];
      }
    }
    __syncthreads();   // sX, sKT ready

    // phase1: Delta[t,r] = D X  (A = D rows t, B = X^T rows r)
    f32x4 Dacc = {0,0,0,0};
    #pragma unroll
    for (int s = 0; s < 2; ++s){
      int kb = s*32 + quad*8;
      bf16x8 ad = frag(cD, wv*16+lm, kb);
      bf16x8 bx = frag(sX, lm, kb);
      Dacc = __builtin_amdgcn_mfma_f32_16x16x32_bf16(ad, bx, Dacc, 0, 0, 0);
    }
    #pragma unroll
    for (int rr = 0; rr < 4; ++rr){
      int t = wv*16 + quad*4 + rr;
      sDT[lm*64 + SWZ(lm, t)] = f2bf(Dacc[rr]);
    }
    __syncthreads();   // sDT ready

    // phase2: O = Mq + Bq Delta ; W += Delta^T K
    f32x4 Oacc = Mqacc;
    #pragma unroll
    for (int s = 0; s < 2; ++s){
      int kb = s*32 + quad*8;
      bf16x8 ab = frag(sB1, wv*16+lm, kb);
      bf16x8 bd = frag(sDT, lm, kb);
      Oacc = __builtin_amdgcn_mfma_f32_16x16x32_bf16(ab, bd, Oacc, 0, 0, 0);
      bf16x8 adt = frag(sDT, lm, kb);
      bf16x8 bkt = frag(sKT, wv*16+lm, kb);
      Wacc = __builtin_amdgcn_mfma_f32_16x16x32_bf16(adt, bkt, Wacc, 0, 0, 0);
    }
    #pragma unroll
    for (int rr = 0; rr < 4; ++rr){
      int tabs = ch*CHK + wv*16 + quad*4 + rr;
      float sz = (rr==0)?sz0:(rr==1)?sz1:(rr==2)?sz2:sz3;
      lo[lobase + (size_t)tabs*(BSZ*DMODEL) + lm] = f2bf(Oacc[rr] * sz);
    }
    __syncthreads();   // all sB1 (and phase2 LDS) reads of this chunk done
    if (ch + 1 < NCH) dma_b(ch + 1);   // refill single-buffered sB1
    // spill W strip (rows r = quad*4+rr, cols d = wv*16+lm); next loop-top
    // barrier orders these writes before phase0's sW reads.
    #pragma unroll
    for (int rr = 0; rr < 4; ++rr){
      int r = quad*4 + rr, d = wv*16 + lm;
      sW[r*64 + SWZ(r, d)] = f2bf(Wacc[rr]);
    }
  }
}

// ------------------------------------------------------------------ residual + layernorm (sums split-K partials)
__global__ __launch_bounds__(256) void ln_kernel(
    const float* __restrict__ hin, const float* __restrict__ a0,
    const float* __restrict__ a1,
    const float* __restrict__ g, const float* __restrict__ bta,
    float* __restrict__ out){
  int row = blockIdx.x, tid = threadIdx.x;
  size_t rb = (size_t)row * DMODEL;
  float4 hv = ((const float4*)(hin + rb))[tid];
  float4 v0 = ((const float4*)(a0 + rb))[tid];
  float4 v1 = ((const float4*)(a1 + rb))[tid];
  float4 x;
  x.x = hv.x + v0.x + v1.x; x.y = hv.y + v0.y + v1.y;
  x.z = hv.z + v0.z + v1.z; x.w = hv.w + v0.w + v1.w;
  float s  = x.x + x.y + x.z + x.w;
  float ss = x.x*x.x + x.y*x.y + x.z*x.z + x.w*x.w;
  #pragma unroll
  for (int off = 1; off < 64; off <<= 1){
    s  += __shfl_xor(s , off, 64);
    ss += __shfl_xor(ss, off, 64);
  }
  __shared__ float ls[4], lq[4];
  int wv = tid >> 6, ln = tid & 63;
  if (ln == 0){ ls[wv] = s; lq[wv] = ss; }
  __syncthreads();
  s  = ls[0] + ls[1] + ls[2] + ls[3];
  ss = lq[0] + lq[1] + lq[2] + lq[3];
  float mu  = s * (1.f/DMODEL);
  float var = ss * (1.f/DMODEL) - mu*mu;
  float rstd = rsqrtf(var + EPSV);
  float4 gv = ((const float4*)g)[tid], bv = ((const float4*)bta)[tid];
  float4 o;
  o.x = (x.x-mu)*rstd*gv.x + bv.x;
  o.y = (x.y-mu)*rstd*gv.y + bv.y;
  o.z = (x.z-mu)*rstd*gv.z + bv.z;
  o.w = (x.w-mu)*rstd*gv.w + bv.w;
  ((float4*)(out + rb))[tid] = o;
}

// ------------------------------------------------------------------ launch
// Workspace budget ~218 MB (ws overflow at ~251 MB killed rounds 3/4/7).
extern "C" void kernel_launch(void* const* d_in, const int* in_sizes, int n_in,
                              void* d_out, int out_size, void* d_ws, size_t ws_size,
                              hipStream_t stream){
  const float* h     = (const float*)d_in[0];
  const float* wqkvb = (const float*)d_in[1];
  const float* wo    = (const float*)d_in[2];
  const float* lng   = (const float*)d_in[3];
  const float* lnb   = (const float*)d_in[4];
  float* out = (float*)d_out;

  char* w = (char*)d_ws;
  auto take = [&](size_t bytes)->char*{
    char* p = w; w += (bytes + 255) & ~(size_t)255; return p;
  };
  unsigned short* h_bf    = (unsigned short*)take((size_t)MROWS*DMODEL*2);
  unsigned short* wq_bf   = (unsigned short*)take((size_t)NQPAD*DMODEL*2);
  unsigned short* wo_bf   = (unsigned short*)take((size_t)DMODEL*DMODEL*2);
  unsigned short* qkvb_bf = (unsigned short*)take((size_t)MROWS*NQPAD*2);
  float* attn1 = (float*)take((size_t)MROWS*DMODEL*4 + 4096);   // splitK partial 1
  float* Ab    = (float*)take((size_t)MROWS*DMODEL*4);   // aliased: D+Bq after scan_kden; attn0 after chunk
  float4* scal = (float4*)take((size_t)64*SLEN*16 + 4096);
  unsigned short* lo_bf = (unsigned short*)take((size_t)MROWS*DMODEL*2);
  float* Sseg = (float*)take((size_t)64*NSEG*64*4);
  unsigned short* kb16 = (unsigned short*)take((size_t)MROWS*DMODEL*2);
  unsigned short* qb16 = (unsigned short*)take((size_t)MROWS*DMODEL*2);
  unsigned short* vb16 = (unsigned short*)take((size_t)MROWS*DMODEL*2);
  unsigned short* Dg = (unsigned short*)Ab;
  unsigned short* Bg = (unsigned short*)Ab + (size_t)64*NCH*4096;
  float* attn0 = Ab;

  cast3_kernel<<<2048, 256, 0, stream>>>(h, h_bf, MROWS*DMODEL/4,
                                         wqkvb, wq_bf, NQKVB*DMODEL/4,
                                         wo, wo_bf, DMODEL*DMODEL/4);

  gemm8p_kernel<true, false><<<(MROWS/256)*(NQPAD/256), 512, 0, stream>>>(
      h_bf, wq_bf, qkvb_bf, nullptr, NQPAD, DMODEL, DMODEL, MROWS/256);

  segsum_kernel<<<dim3(64, NSEG), 64, 0, stream>>>(qkvb_bf, Sseg);
  scan_kden_kernel<<<dim3(64, NSEG), 64, 0, stream>>>(qkvb_bf, Sseg, qb16, vb16, kb16, scal);
  precomp_kernel<<<64*NCH, 64, 0, stream>>>(kb16, qb16, scal, Dg, Bg);
  chunk_kernel<<<dim3(64, 4), 256, 0, stream>>>(kb16, qb16, vb16, Dg, Bg, scal, lo_bf);

  // split-K=2: 256 blocks (full machine), halves write fp32 partials summed in ln
  gemm8p_kernel<false, true><<<2*(MROWS/256)*(DMODEL/256), 512, 0, stream>>>(
      lo_bf, wo_bf, attn0, attn1, DMODEL, DMODEL/2, DMODEL, MROWS/256);

  ln_kernel<<<MROWS, 256, 0, stream>>>(h, attn0, attn1, lng, lnb, out);
  (void)in_sizes; (void)n_in; (void)out_size; (void)ws_size;
}

// Round 13
// 355.796 us; speedup vs baseline: 1.0549x; 1.0043x over previous
//
#include <hip/hip_runtime.h>
#include <cstdint>
#include <cstddef>

#define D_HEAD   64
#define NHEAD    16
#define DMODEL   1024
#define SLEN     2048
#define BSZ      4
#define MROWS    (SLEN*BSZ)            // 8192
#define NQKVB    (NHEAD*(3*D_HEAD+1))  // 3088
#define NQPAD    3328                  // padded to 13*256 for the 256-tile GEMM
#define EPSV     1e-5f
#define SCALEV   0.125f                // 1/sqrt(64)
#define CHK      64                    // chunk length
#define NCH      (SLEN/CHK)            // 32

typedef short bf16x8 __attribute__((ext_vector_type(8)));
typedef float f32x4  __attribute__((ext_vector_type(4)));

__device__ __forceinline__ unsigned short f2bf(float f){
  unsigned int u = __float_as_uint(f);
  u = (u + 0x7fffu + ((u >> 16) & 1u)) >> 16;   // RNE
  return (unsigned short)u;
}
__device__ __forceinline__ float bf2f(unsigned short s){
  return __uint_as_float(((unsigned int)s) << 16);
}

__device__ __forceinline__ void gload_lds16(const unsigned short* g, unsigned short* l){
  __builtin_amdgcn_global_load_lds((const __attribute__((address_space(1))) void*)g,
                                   (__attribute__((address_space(3))) void*)l, 16, 0, 0);
}

// swizzled in-row offset: XOR the 8-element block index with (row&7)
#define SWZ(row, col) ((col) ^ (((row)&7)<<3))

// ------------------------------------------------------------------ fused casts
__global__ void cast3_kernel(const float* __restrict__ s0, unsigned short* __restrict__ d0, int n0,
                             const float* __restrict__ s1, unsigned short* __restrict__ d1, int n1,
                             const float* __restrict__ s2, unsigned short* __restrict__ d2, int n2){
  int total = n0 + n1 + n2;
  int stride = gridDim.x * blockDim.x;
  for (int i = blockIdx.x*blockDim.x + threadIdx.x; i < total; i += stride){
    const float* s; unsigned short* d; int j = i;
    if (j < n0){ s = s0; d = d0; }
    else if (j < n0 + n1){ j -= n0; s = s1; d = d1; }
    else { j -= n0 + n1; s = s2; d = d2; }
    float4 f = ((const float4*)s)[j];
    ushort4 u;
    u.x = f2bf(f.x); u.y = f2bf(f.y); u.z = f2bf(f.z); u.w = f2bf(f.w);
    ((ushort4*)d)[j] = u;
  }
}

// ------------------------------------------------------------------ GEMM (NT), 256x256 8-phase template
// BM=BN=256, BK=64, 8 waves (2M x 4N), 512 threads, 128 KiB LDS double-buffer.
// 128 KB LDS => exactly 1 block/CU (Occupancy ~15%): all hiding is intra-block,
// which is why the barrier diet (r11/r12: 16->6/iter) was the binding lever.
// Structural floor at this shape ~74 us (29% MfmaUtil) — parked.
// Counted vmcnt(2) publishes at phases 4/8; 2D-chunked XCD mapping (r6).
// OUT_BF16 selects the C/C2 element type (bf16 partials for splitK, r13).
#define GBAR  do{ asm volatile("" ::: "memory"); __builtin_amdgcn_s_barrier(); asm volatile("" ::: "memory"); }while(0)
#define WVM2  asm volatile("s_waitcnt vmcnt(2)" ::: "memory")
#define WLG0  asm volatile("s_waitcnt lgkmcnt(0)" ::: "memory")
#define WLG8  asm volatile("s_waitcnt lgkmcnt(8)" ::: "memory")

#define LDA(sb_, mih_) do{ \
  _Pragma("unroll") \
  for (int m2 = 0; m2 < 4; ++m2) \
    _Pragma("unroll") \
    for (int ks = 0; ks < 2; ++ks) \
      aF[m2][ks] = frag(sb_, wmi*128 + (mih_)*64 + m2*16 + lm, ks); \
}while(0)

#define LDB(sb_, nih_) do{ \
  _Pragma("unroll") \
  for (int n2 = 0; n2 < 2; ++n2) \
    _Pragma("unroll") \
    for (int ks = 0; ks < 2; ++ks) \
      bF[(nih_)*2+n2][ks] = frag(sb_, wni*64 + (nih_)*32 + n2*16 + lm, ks); \
}while(0)

#define MMA(mih_, nih_) do{ \
  __builtin_amdgcn_s_setprio(1); \
  _Pragma("unroll") \
  for (int m2 = 0; m2 < 4; ++m2) \
    _Pragma("unroll") \
    for (int n2 = 0; n2 < 2; ++n2) \
      _Pragma("unroll") \
      for (int ks = 0; ks < 2; ++ks) \
        acc[(mih_)*4+m2][(nih_)*2+n2] = __builtin_amdgcn_mfma_f32_16x16x32_bf16( \
            aF[m2][ks], bF[(nih_)*2+n2][ks], acc[(mih_)*4+m2][(nih_)*2+n2], 0, 0, 0); \
  __builtin_amdgcn_s_setprio(0); \
}while(0)

template<bool OUT_BF16, bool SPLITK>
__global__ __launch_bounds__(512, 2) void gemm8p_kernel(
    const unsigned short* __restrict__ A, const unsigned short* __restrict__ B,
    void* __restrict__ C, void* __restrict__ C2, int N, int K, int lda, int tm){
  __shared__ __align__(16) unsigned short sA[2][256*64];
  __shared__ __align__(16) unsigned short sB[2][256*64];
  int tid = threadIdx.x;
  int wv = tid >> 6, ln = tid & 63, lm = ln & 15, quad = ln >> 4;
  // 2D-chunked bijective XCD mapping (requires tm%8==0; grid%8==0):
  //   xcd = wg&7 owns bm in [xcd*CM, (xcd+1)*CM), bn-major walk.
  int wg = blockIdx.x;
  int kh = 0;
  if (SPLITK){ int half = gridDim.x >> 1; if (wg >= half){ kh = 1; wg -= half; } }
  int xcd = wg & 7, l = wg >> 3;
  int CM = tm >> 3;
  int bn = l / CM, bm = xcd*CM + (l - bn*CM);
  int m0 = bm << 8, n0 = bn << 8;
  int wmi = wv >> 2, wni = wv & 3;
  const unsigned short* Ag = A + (size_t)m0*lda + (size_t)kh*K;
  const unsigned short* Bg = B + (size_t)n0*lda + (size_t)kh*K;

  f32x4 acc[8][4] = {};
  bf16x8 aF[4][2], bF[4][2];

  // iteration-invariant staging geometry: round r covers linear elem-blocks
  // e = r*512 + wv*64 + ln ; row = e>>3 ; cb = e&7 ; source col-block inverse-swizzled.
  int e0 = wv*64 + ln;
  int r0row = e0 >> 3, r0cb = e0 & 7;
  int e1 = 512 + e0;
  int r1row = e1 >> 3, r1cb = e1 & 7;
  size_t gsrc0 = (size_t)r0row*lda + ((r0cb ^ (r0row & 7)) << 3);
  size_t gsrc1 = (size_t)r1row*lda + ((r1cb ^ (r1row & 7)) << 3);
  int ldst0 = (wv*64) * 8;           // wave-uniform LDS elem offsets
  int ldst1 = (512 + wv*64) * 8;

  auto stage = [&](const unsigned short* g, unsigned short* sb, int h, int kt){
    gload_lds16(g + (size_t)h*128*lda + kt + gsrc0, sb + h*8192 + ldst0);
    gload_lds16(g + (size_t)h*128*lda + kt + gsrc1, sb + h*8192 + ldst1);
  };
  auto frag = [&](const unsigned short* sb, int row, int ks)->bf16x8 {
    return *(const bf16x8*)(sb + row*64 + ((((ks<<2)+quad) ^ (row & 7)) << 3));
  };

  // prologue: tile0 -> buf0 (4 half-tiles), tile1 A-h0 -> buf1; publish tile0.
  stage(Ag, sA[0], 0, 0);
  stage(Ag, sA[0], 1, 0);
  stage(Bg, sB[0], 0, 0);
  stage(Bg, sB[0], 1, 0);
  stage(Ag, sA[1], 0, 64);
  WVM2;
  GBAR;

  int nit = K >> 7;                   // 2 K-tiles (BK=64) per iteration
  for (int i = 0; i < nit; ++i){
    int k1 = (i<<7) + 64;             // odd tile of this iteration
    int k2 = ((i<<7) + 128) & (K-1);  // next even tile (wraps harmlessly at end)
    int k3 = ((i<<7) + 192) & (K-1);  // next odd tile

    // phase 1: Q(mi0-3 x ni0-1) on buf0  [pre-barrier kept: alignment]
    LDA(sA[0], 0); LDB(sB[0], 0);
    stage(Ag, sA[1], 1, k1);
    WLG8;
    GBAR; WLG0; MMA(0,0);
    // phase 2: Q(mi0-3 x ni2-3)  [no barriers]
    LDB(sB[0], 1);
    stage(Bg, sB[1], 0, k1);
    WLG0; MMA(0,1);
    // phase 3: Q(mi4-7 x ni0-1)  [END BARRIER KEPT: phase 4 stages into buf0]
    LDA(sA[0], 1);
    stage(Bg, sB[1], 1, k1);
    WLG0; MMA(1,0); GBAR;
    // phase 4: Q(mi4-7 x ni2-3); publish buf1 (WVM2 after reg-only MMA)
    stage(Ag, sA[0], 0, k2);
    MMA(1,1); WVM2; GBAR;
    // phase 5: buf1  [pre-barrier kept: alignment]
    LDA(sA[1], 0); LDB(sB[1], 0);
    stage(Ag, sA[0], 1, k2);
    WLG8;
    GBAR; WLG0; MMA(0,0);
    // phase 6  [no barriers]
    LDB(sB[1], 1);
    stage(Bg, sB[0], 0, k2);
    WLG0; MMA(0,1);
    // phase 7  [END BARRIER KEPT: phase 8 stages into buf1]
    LDA(sA[1], 1);
    stage(Bg, sB[0], 1, k2);
    WLG0; MMA(1,0); GBAR;
    // phase 8: publish buf0 (next even tile)
    stage(Ag, sA[1], 0, k3);
    MMA(1,1); WVM2; GBAR;
  }
  asm volatile("s_waitcnt vmcnt(0)" ::: "memory");  // drain trailing LDS-DMA before exit

  void* Cp = (SPLITK && kh) ? C2 : C;
  #pragma unroll
  for (int mi = 0; mi < 8; ++mi){
    int rowm = m0 + wmi*128 + mi*16 + quad*4;
    #pragma unroll
    for (int ni = 0; ni < 4; ++ni){
      int col = n0 + wni*64 + ni*16 + lm;
      size_t cb = (size_t)rowm * N + col;
      #pragma unroll
      for (int rr = 0; rr < 4; ++rr){
        float v = acc[mi][ni][rr];
        if (OUT_BF16) ((unsigned short*)Cp)[cb + (size_t)rr*N] = f2bf(v);
        else          ((float*)Cp)[cb + (size_t)rr*N] = v;
      }
    }
  }
}

#undef LDA
#undef LDB
#undef MMA
#undef GBAR
#undef WVM2
#undef WLG0
#undef WLG8

// ------------------------------------------------------------------ segmented cumsum over l
// NSEG=64 (SEGL=32): 4096 waves -> 16 waves/CU for the serial latency chains.
// kn is RECOMPUTED from qkvb_bf (bit-exact vs the old prep path).
#define NSEG 64
#define SEGL (SLEN/NSEG)   // 32
__global__ __launch_bounds__(64) void segsum_kernel(
    const unsigned short* __restrict__ qkvb, float* __restrict__ S){
  int bh = blockIdx.x, seg = blockIdx.y, ln = threadIdx.x;
  int b = bh >> 4, h = bh & 15;
  float s = 0.f;
  for (int i = 0; i < SEGL; ++i){
    int t = seg*SEGL + i;
    size_t rb = (size_t)(t*4+b) * NQPAD + (size_t)h*193;
    float kr = bf2f(qkvb[rb + 64 + ln]);
    float k1 = kr > 0.f ? kr + 1.f : __expf(kr);   // elu(x)+1
    float sk = k1;
    #pragma unroll
    for (int off = 1; off < 64; off <<= 1) sk += __shfl_xor(sk, off, 64);
    s += k1 / sk;
  }
  S[((size_t)bh*NSEG + seg)*64 + ln] = s;
}

// ------------------------------------------------------------------ fused prep + scan + denominators
// Recomputes qn/kn from qkvb_bf (bit-exact vs old prep), walks the inclusive
// cumsum, computes the three denominator reductions, and writes ALL downstream
// inputs: qb16/vb16 (bf16), kb16 (normalized bf16, swizzled), scal.
__global__ __launch_bounds__(64) void scan_kden_kernel(
    const unsigned short* __restrict__ qkvb, const float* __restrict__ S,
    unsigned short* __restrict__ qb16, unsigned short* __restrict__ vb16,
    unsigned short* __restrict__ kb16, float4* __restrict__ scal){
  int bh = blockIdx.x, seg = blockIdx.y, ln = threadIdx.x;
  int b = bh >> 4, h = bh & 15;
  float acc = 0.f;
  for (int s = 0; s < seg; ++s) acc += S[((size_t)bh*NSEG + s)*64 + ln];
  for (int i = 0; i < SEGL; ++i){
    int t = seg*SEGL + i;
    size_t rb = (size_t)(t*4+b) * NQPAD + (size_t)h*193;
    float qr = bf2f(qkvb[rb + ln]);
    float kr = bf2f(qkvb[rb + 64 + ln]);
    float vr = bf2f(qkvb[rb + 128 + ln]);
    float q1 = qr > 0.f ? qr + 1.f : __expf(qr);   // elu(x)+1
    float k1 = kr > 0.f ? kr + 1.f : __expf(kr);
    float sq = q1, sk = k1;
    #pragma unroll
    for (int off = 1; off < 64; off <<= 1){
      sq += __shfl_xor(sq, off, 64);
      sk += __shfl_xor(sk, off, 64);
    }
    float qn = q1 / sq, kn = k1 / sk;
    acc += kn;
    float a = acc;
    float d0 = (a - kn)*kn, d1 = a*qn, d2 = kn*qn;
    #pragma unroll
    for (int off = 1; off < 64; off <<= 1){
      d0 += __shfl_xor(d0, off, 64);
      d1 += __shfl_xor(d1, off, 64);
      d2 += __shfl_xor(d2, off, 64);
    }
    float kd  = (t == 0) ? 1.f : d0;
    float inv = 1.f / (kd + EPSV);
    float kf = kn * inv;
    size_t row = ((size_t)bh*SLEN + t)*64;
    qb16[row + SWZ(t, ln)] = f2bf(qn);
    vb16[row + ln] = f2bf(vr);
    kb16[row + SWZ(t, ln)] = f2bf(kf);
    if (ln == 0){
      float br = bf2f(qkvb[rb + 192]);
      float sb = 1.f / (1.f + __expf(-br));
      scal[(size_t)bh*SLEN + t] = make_float4(sb * kd, d2 * inv, SCALEV/(d1 + EPSV), 0.f);
    }
  }
}

// ------------------------------------------------------------------ precompute per (bh,chunk):
// Akk = K K^T (fp32, LDS), Bq = tril(Q K^T) incl diag (bf16 -> global, SWIZZLED),
// Dmat = (I + diag(b')*strictlow(Akk))^-1 diag(b')  (bf16 -> global, SWIZZLED).
// r13: the per-row reduction uses 4 independent accumulators (chain depth /4).
__global__ __launch_bounds__(64, 1) void precomp_kernel(
    const unsigned short* __restrict__ K16, const unsigned short* __restrict__ Q16,
    const float4* __restrict__ scal,
    unsigned short* __restrict__ Dg, unsigned short* __restrict__ Bg){
  __shared__ __align__(16) float sA[64*64];
  __shared__ float sbp[64];
  int inst = blockIdx.x;
  int bh = inst >> 5, ch = inst & 31;
  int ln = threadIdx.x, lm = ln & 15, quad = ln >> 4;
  const unsigned short* Kg = K16 + ((size_t)bh*SLEN + ch*CHK)*64;
  const unsigned short* Qg = Q16 + ((size_t)bh*SLEN + ch*CHK)*64;

  // Akk GEMM
  {
    f32x4 acc[4][4] = {};
    #pragma unroll
    for (int s = 0; s < 2; ++s){
      bf16x8 kf[4];
      #pragma unroll
      for (int i = 0; i < 4; ++i){
        int row = i*16+lm;
        kf[i] = *(const bf16x8*)(Kg + (size_t)row*64 + SWZ(row, s*32 + quad*8));
      }
      #pragma unroll
      for (int mi = 0; mi < 4; ++mi)
        #pragma unroll
        for (int ni = 0; ni < 4; ++ni)
          acc[mi][ni] = __builtin_amdgcn_mfma_f32_16x16x32_bf16(kf[mi], kf[ni], acc[mi][ni], 0, 0, 0);
    }
    #pragma unroll
    for (int mi = 0; mi < 4; ++mi)
      #pragma unroll
      for (int ni = 0; ni < 4; ++ni)
        #pragma unroll
        for (int rr = 0; rr < 4; ++rr)
          sA[(mi*16+quad*4+rr)*64 + ni*16+lm] = acc[mi][ni][rr];
  }
  sbp[ln] = scal[(size_t)bh*SLEN + ch*CHK + ln].x;
  __syncthreads();

  // Bq GEMM, masked swizzled store
  {
    f32x4 acc[4][4] = {};
    #pragma unroll
    for (int s = 0; s < 2; ++s){
      bf16x8 kf[4], qf[4];
      #pragma unroll
      for (int i = 0; i < 4; ++i){
        int row = i*16+lm;
        kf[i] = *(const bf16x8*)(Kg + (size_t)row*64 + SWZ(row, s*32 + quad*8));
        qf[i] = *(const bf16x8*)(Qg + (size_t)row*64 + SWZ(row, s*32 + quad*8));
      }
      #pragma unroll
      for (int mi = 0; mi < 4; ++mi)
        #pragma unroll
        for (int ni = 0; ni < 4; ++ni)
          acc[mi][ni] = __builtin_amdgcn_mfma_f32_16x16x32_bf16(qf[mi], kf[ni], acc[mi][ni], 0, 0, 0);
    }
    size_t io = (size_t)inst*4096;
    #pragma unroll
    for (int mi = 0; mi < 4; ++mi)
      #pragma unroll
      for (int ni = 0; ni < 4; ++ni)
        #pragma unroll
        for (int rr = 0; rr < 4; ++rr){
          int t = mi*16+quad*4+rr, j = ni*16+lm;
          float v = (j <= t) ? acc[mi][ni][rr] : 0.f;
          Bg[io + (size_t)t*64 + SWZ(t, j)] = f2bf(v);
        }
  }

  // triangular inversion: X = (I + diag(b')L)^-1 diag(b'); lane = column j.
  // 4 independent accumulators break the serial FMA chain (depth/4).
  {
    float x[64];
    x[0] = (ln == 0) ? sbp[0] : 0.f;
    #pragma unroll
    for (int i = 1; i < 64; ++i){
      float bi = sbp[i];
      float s0 = 0.f, s1 = 0.f, s2 = 0.f, s3 = 0.f;
      #pragma unroll
      for (int m4 = 0; m4*4 < i; ++m4){
        float4 a = *(const float4*)&sA[i*64 + m4*4];
        if (m4*4+0 < i) s0 += a.x * x[m4*4+0];
        if (m4*4+1 < i) s1 += a.y * x[m4*4+1];
        if (m4*4+2 < i) s2 += a.z * x[m4*4+2];
        if (m4*4+3 < i) s3 += a.w * x[m4*4+3];
      }
      float s = (s0 + s1) + (s2 + s3);
      x[i] = ((ln == i) ? bi : 0.f) - bi*s;
    }
    size_t io = (size_t)inst*4096;
    #pragma unroll
    for (int i = 0; i < 64; ++i)
      Dg[io + (size_t)i*64 + SWZ(i, ln)] = f2bf(x[i]);
  }
}

// ------------------------------------------------------------------ chunked delta-rule, MFMA, r-split 4, 2 blocks/CU
// grid (64 bh, 4 rgroup); each block owns W rows r = rg*16..rg*16+15.
// LDS 74 KB (sB1 single-buffered, refilled after its post-phase2 barrier) ->
// 2 blocks/CU so the co-resident block hides barrier/vmcnt stalls.
__global__ __launch_bounds__(256, 2) void chunk_kernel(
    const unsigned short* __restrict__ K16, const unsigned short* __restrict__ Q16,
    const unsigned short* __restrict__ V16,
    const unsigned short* __restrict__ Dg, const unsigned short* __restrict__ Bg,
    const float4* __restrict__ scal, unsigned short* __restrict__ lo){
  __shared__ __align__(16) unsigned short sK[2][4096];   // K (t,d) swz
  __shared__ __align__(16) unsigned short sQ[2][4096];   // Q (t,d) swz
  __shared__ __align__(16) unsigned short sD[2][4096];   // D (t,j) swz
  __shared__ __align__(16) unsigned short sB1[4096];     // Bq (t,j) swz, single-buf
  __shared__ __align__(16) unsigned short sKT[4096];     // K^T (d,t) swz
  __shared__ __align__(16) unsigned short sV[2][1024];   // V strip (t, 16r) linear
  __shared__ __align__(16) unsigned short sX[1024];      // X^T (16r, t) swz
  __shared__ __align__(16) unsigned short sDT[1024];     // Delta^T (16r, t) swz
  __shared__ __align__(16) unsigned short sW[1024];      // W strip (16r, d) swz
  int bh = blockIdx.x, rg = blockIdx.y;
  int tid = threadIdx.x, wv = tid >> 6, ln = tid & 63, lm = ln & 15, quad = ln >> 4;
  size_t sb = (size_t)bh*SLEN*64;
  const unsigned short* Kg = K16 + sb;
  const unsigned short* Qg = Q16 + sb;
  const unsigned short* Vg = V16 + sb;
  const float4* scp = scal + (size_t)bh*SLEN;
  size_t lobase = (size_t)(bh>>4)*DMODEL + (size_t)(bh&15)*64 + rg*16;

  auto dma8 = [&](const unsigned short* g, unsigned short* s){
    #pragma unroll
    for (int it = 0; it < 2; ++it)
      gload_lds16(g + (wv*2+it)*512 + ln*8, s + (wv*2+it)*512);
  };
  auto dma_kqdv = [&](int ch, int p){
    size_t co = (size_t)ch*CHK*64;
    dma8(Kg + co, sK[p]);
    dma8(Qg + co, sQ[p]);
    dma8(Dg + ((size_t)bh*NCH + ch)*4096, sD[p]);
    if (wv == 0){
      gload_lds16(Vg + co + (size_t)(ln>>1)*64 + rg*16 + (ln&1)*8, sV[p]);
      gload_lds16(Vg + co + (size_t)(32 + (ln>>1))*64 + rg*16 + (ln&1)*8, sV[p] + 512);
    }
  };
  auto dma_b = [&](int ch){
    dma8(Bg + ((size_t)bh*NCH + ch)*4096, sB1);
  };
  auto frag = [&](const unsigned short* S, int row, int kb)->bf16x8 {
    return *(const bf16x8*)(S + row*64 + SWZ(row, kb));
  };

  if (tid < 128) ((uint4*)sW)[tid] = make_uint4(0u,0u,0u,0u);
  f32x4 Wacc = {0,0,0,0};
  dma_kqdv(0, 0);
  dma_b(0);

  for (int ch = 0; ch < NCH; ++ch){
    int p = ch & 1;
    const unsigned short* cK = sK[p];
    const unsigned short* cQ = sQ[p];
    const unsigned short* cD = sD[p];
    const unsigned short* cV = sV[p];
    int tb = ch*CHK + wv*16 + quad*4;
    float sz0 = scp[tb+0].z, sz1 = scp[tb+1].z, sz2 = scp[tb+2].z, sz3 = scp[tb+3].z;
    __builtin_amdgcn_s_waitcnt(0x0F70);   // vmcnt(0): this chunk's DMA (incl. late B)
    __syncthreads();                      // publish buf p + sB1 + sW spills
    if (ch + 1 < NCH) dma_kqdv(ch + 1, p ^ 1);   // overlap next K/Q/D/V DMA with phases 0-2

    // phase0: M = K W^T, Mq = Q W^T (wave = t-tile wv)
    f32x4 Macc = {0,0,0,0}, Mqacc = {0,0,0,0};
    #pragma unroll
    for (int s = 0; s < 2; ++s){
      int kb = s*32 + quad*8;
      bf16x8 ak = frag(cK, wv*16+lm, kb);
      bf16x8 aq = frag(cQ, wv*16+lm, kb);
      bf16x8 bw = frag(sW, lm, kb);
      Macc  = __builtin_amdgcn_mfma_f32_16x16x32_bf16(ak, bw, Macc, 0, 0, 0);
      Mqacc = __builtin_amdgcn_mfma_f32_16x16x32_bf16(aq, bw, Mqacc, 0, 0, 0);
    }
    // K-transpose read: thread -> row t = ln, cols d0..d0+15 (d0 = wv*16)
    int d0 = wv*16;
    uint4 kr0 = *(const uint4*)(cK + ln*64 + SWZ(ln, d0));
    uint4 kr1 = *(const uint4*)(cK + ln*64 + SWZ(ln, d0+8));
    // X = V - M; scatter X^T into sX
    #pragma unroll
    for (int rr = 0; rr < 4; ++rr){
      int t = wv*16 + quad*4 + rr;
      float x = bf2f(cV[t*16 + lm]) - Macc[rr];
      sX[lm*64 + SWZ(lm, t)] = f2bf(x);
    }
    // scatter K^T into sKT (per e: whole wave writes one row d)
    {
      const unsigned short* k0p = (const unsigned short*)&kr0;
      const unsigned short* k1p = (const unsigned short*)&kr1;
      #pragma unroll
      for (int e = 0; e < 8; ++e){
        int d = d0 + e;
        sKT[d*64 + SWZ(d, ln)] = k0p[e];
      }
      #pragma unroll
      for (int e = 0; e < 8; ++e){
        int d = d0 + 8 + e;
        sKT[d*64 + SWZ(d, ln)] = k1p[e];
      }
    }
    __syncthreads();   // sX, sKT ready

    // phase1: Delta[t,r] = D X  (A = D rows t, B = X^T rows r)
    f32x4 Dacc = {0,0,0,0};
    #pragma unroll
    for (int s = 0; s < 2; ++s){
      int kb = s*32 + quad*8;
      bf16x8 ad = frag(cD, wv*16+lm, kb);
      bf16x8 bx = frag(sX, lm, kb);
      Dacc = __builtin_amdgcn_mfma_f32_16x16x32_bf16(ad, bx, Dacc, 0, 0, 0);
    }
    #pragma unroll
    for (int rr = 0; rr < 4; ++rr){
      int t = wv*16 + quad*4 + rr;
      sDT[lm*64 + SWZ(lm, t)] = f2bf(Dacc[rr]);
    }
    __syncthreads();   // sDT ready

    // phase2: O = Mq + Bq Delta ; W += Delta^T K
    f32x4 Oacc = Mqacc;
    #pragma unroll
    for (int s = 0; s < 2; ++s){
      int kb = s*32 + quad*8;
      bf16x8 ab = frag(sB1, wv*16+lm, kb);
      bf16x8 bd = frag(sDT, lm, kb);
      Oacc = __builtin_amdgcn_mfma_f32_16x16x32_bf16(ab, bd, Oacc, 0, 0, 0);
      bf16x8 adt = frag(sDT, lm, kb);
      bf16x8 bkt = frag(sKT, wv*16+lm, kb);
      Wacc = __builtin_amdgcn_mfma_f32_16x16x32_bf16(adt, bkt, Wacc, 0, 0, 0);
    }
    #pragma unroll
    for (int rr = 0; rr < 4; ++rr){
      int tabs = ch*CHK + wv*16 + quad*4 + rr;
      float sz = (rr==0)?sz0:(rr==1)?sz1:(rr==2)?sz2:sz3;
      lo[lobase + (size_t)tabs*(BSZ*DMODEL) + lm] = f2bf(Oacc[rr] * sz);
    }
    __syncthreads();   // all sB1 (and phase2 LDS) reads of this chunk done
    if (ch + 1 < NCH) dma_b(ch + 1);   // refill single-buffered sB1
    // spill W strip (rows r = quad*4+rr, cols d = wv*16+lm); next loop-top
    // barrier orders these writes before phase0's sW reads.
    #pragma unroll
    for (int rr = 0; rr < 4; ++rr){
      int r = quad*4 + rr, d = wv*16 + lm;
      sW[r*64 + SWZ(r, d)] = f2bf(Wacc[rr]);
    }
  }
}

// ------------------------------------------------------------------ residual + layernorm (sums bf16 split-K partials)
__global__ __launch_bounds__(256) void ln_kernel(
    const float* __restrict__ hin, const unsigned short* __restrict__ a0,
    const unsigned short* __restrict__ a1,
    const float* __restrict__ g, const float* __restrict__ bta,
    float* __restrict__ out){
  int row = blockIdx.x, tid = threadIdx.x;
  size_t rb = (size_t)row * DMODEL;
  float4 hv = ((const float4*)(hin + rb))[tid];
  ushort4 u0 = ((const ushort4*)(a0 + rb))[tid];
  ushort4 u1 = ((const ushort4*)(a1 + rb))[tid];
  float4 x;
  x.x = hv.x + bf2f(u0.x) + bf2f(u1.x);
  x.y = hv.y + bf2f(u0.y) + bf2f(u1.y);
  x.z = hv.z + bf2f(u0.z) + bf2f(u1.z);
  x.w = hv.w + bf2f(u0.w) + bf2f(u1.w);
  float s  = x.x + x.y + x.z + x.w;
  float ss = x.x*x.x + x.y*x.y + x.z*x.z + x.w*x.w;
  #pragma unroll
  for (int off = 1; off < 64; off <<= 1){
    s  += __shfl_xor(s , off, 64);
    ss += __shfl_xor(ss, off, 64);
  }
  __shared__ float ls[4], lq[4];
  int wv = tid >> 6, ln = tid & 63;
  if (ln == 0){ ls[wv] = s; lq[wv] = ss; }
  __syncthreads();
  s  = ls[0] + ls[1] + ls[2] + ls[3];
  ss = lq[0] + lq[1] + lq[2] + lq[3];
  float mu  = s * (1.f/DMODEL);
  float var = ss * (1.f/DMODEL) - mu*mu;
  float rstd = rsqrtf(var + EPSV);
  float4 gv = ((const float4*)g)[tid], bv = ((const float4*)bta)[tid];
  float4 o;
  o.x = (x.x-mu)*rstd*gv.x + bv.x;
  o.y = (x.y-mu)*rstd*gv.y + bv.y;
  o.z = (x.z-mu)*rstd*gv.z + bv.z;
  o.w = (x.w-mu)*rstd*gv.w + bv.w;
  ((float4*)(out + rb))[tid] = o;
}

// ------------------------------------------------------------------ launch
// Workspace budget ~218 MB (ws overflow at ~251 MB killed rounds 3/4/7).
extern "C" void kernel_launch(void* const* d_in, const int* in_sizes, int n_in,
                              void* d_out, int out_size, void* d_ws, size_t ws_size,
                              hipStream_t stream){
  const float* h     = (const float*)d_in[0];
  const float* wqkvb = (const float*)d_in[1];
  const float* wo    = (const float*)d_in[2];
  const float* lng   = (const float*)d_in[3];
  const float* lnb   = (const float*)d_in[4];
  float* out = (float*)d_out;

  char* w = (char*)d_ws;
  auto take = [&](size_t bytes)->char*{
    char* p = w; w += (bytes + 255) & ~(size_t)255; return p;
  };
  unsigned short* h_bf    = (unsigned short*)take((size_t)MROWS*DMODEL*2);
  unsigned short* wq_bf   = (unsigned short*)take((size_t)NQPAD*DMODEL*2);
  unsigned short* wo_bf   = (unsigned short*)take((size_t)DMODEL*DMODEL*2);
  unsigned short* qkvb_bf = (unsigned short*)take((size_t)MROWS*NQPAD*2);
  unsigned short* attn1 = (unsigned short*)take((size_t)MROWS*DMODEL*2 + 4096);  // splitK bf16 partial 1
  float* Ab    = (float*)take((size_t)MROWS*DMODEL*4);   // aliased: D+Bq after scan_kden; attn0 (bf16) after chunk
  float4* scal = (float4*)take((size_t)64*SLEN*16 + 4096);
  unsigned short* lo_bf = (unsigned short*)take((size_t)MROWS*DMODEL*2);
  float* Sseg = (float*)take((size_t)64*NSEG*64*4);
  unsigned short* kb16 = (unsigned short*)take((size_t)MROWS*DMODEL*2);
  unsigned short* qb16 = (unsigned short*)take((size_t)MROWS*DMODEL*2);
  unsigned short* vb16 = (unsigned short*)take((size_t)MROWS*DMODEL*2);
  unsigned short* Dg = (unsigned short*)Ab;
  unsigned short* Bg = (unsigned short*)Ab + (size_t)64*NCH*4096;
  unsigned short* attn0 = (unsigned short*)Ab;

  cast3_kernel<<<2048, 256, 0, stream>>>(h, h_bf, MROWS*DMODEL/4,
                                         wqkvb, wq_bf, NQKVB*DMODEL/4,
                                         wo, wo_bf, DMODEL*DMODEL/4);

  gemm8p_kernel<true, false><<<(MROWS/256)*(NQPAD/256), 512, 0, stream>>>(
      h_bf, wq_bf, qkvb_bf, nullptr, NQPAD, DMODEL, DMODEL, MROWS/256);

  segsum_kernel<<<dim3(64, NSEG), 64, 0, stream>>>(qkvb_bf, Sseg);
  scan_kden_kernel<<<dim3(64, NSEG), 64, 0, stream>>>(qkvb_bf, Sseg, qb16, vb16, kb16, scal);
  precomp_kernel<<<64*NCH, 64, 0, stream>>>(kb16, qb16, scal, Dg, Bg);
  chunk_kernel<<<dim3(64, 4), 256, 0, stream>>>(kb16, qb16, vb16, Dg, Bg, scal, lo_bf);

  // split-K=2: 256 blocks (full machine), halves write bf16 partials summed in ln
  gemm8p_kernel<true, true><<<2*(MROWS/256)*(DMODEL/256), 512, 0, stream>>>(
      lo_bf, wo_bf, attn0, attn1, DMODEL, DMODEL/2, DMODEL, MROWS/256);

  ln_kernel<<<MROWS, 256, 0, stream>>>(h, attn0, attn1, lng, lnb, out);
  (void)in_sizes; (void)n_in; (void)out_size; (void)ws_size;
}